// Round 2
// baseline (421.260 us; speedup 1.0000x reference)
//
#include <hip/hip_runtime.h>
#include <hip/hip_bf16.h>

// Problem constants (fixed by reference): B=4, C=256, N=2048, H=8, D=32
#define Bx 4
#define Cx 256
#define Nx 2048
#define Hx 8
#define Dx 32

static __device__ __forceinline__ unsigned short f2bf(float f) {
    // round-to-nearest-even bf16 (inputs are finite, no NaN handling needed)
    unsigned int u = __float_as_uint(f);
    u += 0x7fffu + ((u >> 16) & 1u);
    return (unsigned short)(u >> 16);
}

// ---------------------------------------------------------------------------
// Kernel 1: QKV projection.  qkv[b][o][n] = b_qkv[o] + sum_c W[o][c]*x[b][c][n]
// grid (12 o-tiles, 16 n-tiles, 4 b), block 256.  Tile: 64 o x 128 n, K-chunk 64.
// ---------------------------------------------------------------------------
__global__ __launch_bounds__(256, 3) void qkv_kernel(
    const float* __restrict__ x, const float* __restrict__ w,
    const float* __restrict__ bias, float* __restrict__ qkv)
{
    __shared__ float Wl[64][68];    // [c][o]  (transposed W tile)
    __shared__ float Xl[64][132];   // [c][n]
    const int t  = threadIdx.x;
    const int o0 = blockIdx.x * 64;
    const int n0 = blockIdx.y * 128;
    const int b  = blockIdx.z;
    const int og = t >> 4, ng = t & 15;   // 16x16 thread grid, 4o x 8n each

    float acc[4][8];
    #pragma unroll
    for (int i = 0; i < 4; ++i)
        #pragma unroll
        for (int j = 0; j < 8; ++j) acc[i][j] = 0.f;

    for (int cc = 0; cc < Cx; cc += 64) {
        __syncthreads();
        // stage W tile (64 o x 64 c), transposed into Wl[c][o]
        #pragma unroll
        for (int it = 0; it < 4; ++it) {
            const int v = t + it * 256;
            const int oi = v >> 4, c4 = (v & 15) * 4;
            const float4 f = *(const float4*)&w[(size_t)(o0 + oi) * Cx + cc + c4];
            Wl[c4 + 0][oi] = f.x; Wl[c4 + 1][oi] = f.y;
            Wl[c4 + 2][oi] = f.z; Wl[c4 + 3][oi] = f.w;
        }
        // stage X tile (64 c x 128 n)
        #pragma unroll
        for (int it = 0; it < 8; ++it) {
            const int v = t + it * 256;
            const int ci = v >> 5, n4 = (v & 31) * 4;
            *(float4*)&Xl[ci][n4] =
                *(const float4*)&x[((size_t)b * Cx + cc + ci) * Nx + n0 + n4];
        }
        __syncthreads();
        #pragma unroll 8
        for (int c = 0; c < 64; ++c) {
            const float4 w4 = *(const float4*)&Wl[c][og * 4];
            const float4 xa = *(const float4*)&Xl[c][ng * 8];
            const float4 xb = *(const float4*)&Xl[c][ng * 8 + 4];
            const float wr[4] = {w4.x, w4.y, w4.z, w4.w};
            const float xr[8] = {xa.x, xa.y, xa.z, xa.w, xb.x, xb.y, xb.z, xb.w};
            #pragma unroll
            for (int i = 0; i < 4; ++i)
                #pragma unroll
                for (int j = 0; j < 8; ++j)
                    acc[i][j] = fmaf(wr[i], xr[j], acc[i][j]);
        }
    }

    #pragma unroll
    for (int i = 0; i < 4; ++i) {
        const int o = o0 + og * 4 + i;
        const float bv = bias[o];
        float* dst = &qkv[((size_t)b * 768 + o) * Nx + n0 + ng * 8];
        *(float4*)(dst + 0) = make_float4(acc[i][0] + bv, acc[i][1] + bv,
                                          acc[i][2] + bv, acc[i][3] + bv);
        *(float4*)(dst + 4) = make_float4(acc[i][4] + bv, acc[i][5] + bv,
                                          acc[i][6] + bv, acc[i][7] + bv);
    }
}

// ---------------------------------------------------------------------------
// Kernel 2: flash attention (fp32 compute, bf16 P in LDS).
// grid (16 q-tiles, 32 bh), block 256 (4 waves).  Q-tile 128, KV-tile 64.
// Wave w owns q rows [w*32, w*32+32).  lane: qg=lane>>3 (4q each), mg=lane&7.
// QK: thread computes s[4q][8m].  Softmax row-reduce over the 8 mg lanes.
// PV: ms=mg>>1 (m-slice of 16), dg=mg&1 (d-half of 16); combine via shfl_xor.
// ---------------------------------------------------------------------------
__global__ __launch_bounds__(256, 2) void attn_kernel(
    const float* __restrict__ qkv, float* __restrict__ attn_out)
{
    __shared__ float Qlds[32][132];                      // [d][q]  q-tile 128
    __shared__ float Klds[32][68];                       // [d][m]  kv-tile 64
    __shared__ float Vlds[64][36];                       // [m][d]  (d xor-swizzled by m>>4)
    __shared__ __align__(16) unsigned short Plds[4][64][40];  // per-wave P, bf16 [m][q]

    const int t  = threadIdx.x;
    const int q0 = blockIdx.x * 128;
    const int bh = blockIdx.y;
    const int b = bh >> 3, h = bh & 7;
    const int lane = t & 63, wv = t >> 6;
    const int qg = lane >> 3, mg = lane & 7;
    const int ms = mg >> 1, dg = mg & 1;

    const float* qb = qkv + ((size_t)b * 768 + h * 32) * Nx;
    const float* kb = qb + (size_t)256 * Nx;
    const float* vb = qb + (size_t)512 * Nx;
    const float scale = 0.17677669529663688f;   // 1/sqrt(32)

    // stage Q tile once, pre-scaled
    #pragma unroll
    for (int it = 0; it < 4; ++it) {
        const int v = t + it * 256;
        const int d = v >> 5, c4 = (v & 31) * 4;
        float4 f = *(const float4*)&qb[(size_t)d * Nx + q0 + c4];
        f.x *= scale; f.y *= scale; f.z *= scale; f.w *= scale;
        *(float4*)&Qlds[d][c4] = f;
    }

    float m_i[4], l_i[4], o_acc[4][16];
    #pragma unroll
    for (int i = 0; i < 4; ++i) {
        m_i[i] = -3.0e38f; l_i[i] = 0.f;
        #pragma unroll
        for (int j = 0; j < 16; ++j) o_acc[i][j] = 0.f;
    }

    for (int m0 = 0; m0 < Nx; m0 += 64) {
        __syncthreads();   // protect K/V overwrite from previous tile's readers
        #pragma unroll
        for (int it = 0; it < 2; ++it) {
            const int v = t + it * 256;
            const int d = v >> 4, m4 = (v & 15) * 4;
            *(float4*)&Klds[d][m4] = *(const float4*)&kb[(size_t)d * Nx + m0 + m4];
        }
        #pragma unroll
        for (int it = 0; it < 2; ++it) {
            const int v = t + it * 256;
            const int d = v >> 4, m4 = (v & 15) * 4;
            const float4 f = *(const float4*)&vb[(size_t)d * Nx + m0 + m4];
            const float vals[4] = {f.x, f.y, f.z, f.w};
            const int dgw = d >> 4, db = (d >> 2) & 3, dl = d & 3;
            #pragma unroll
            for (int u = 0; u < 4; ++u) {
                const int m = m4 + u;
                const int msm = (m >> 4) & 3;
                Vlds[m][dgw * 16 + ((db ^ msm) << 2) + dl] = vals[u];
            }
        }
        __syncthreads();

        // --- QK^T ---
        float s[4][8];
        #pragma unroll
        for (int i = 0; i < 4; ++i)
            #pragma unroll
            for (int j = 0; j < 8; ++j) s[i][j] = 0.f;

        #pragma unroll 8
        for (int d = 0; d < 32; ++d) {
            const float4 q4  = *(const float4*)&Qlds[d][wv * 32 + qg * 4];
            const float4 ka  = *(const float4*)&Klds[d][mg * 8];
            const float4 kb4 = *(const float4*)&Klds[d][mg * 8 + 4];
            const float qr[4] = {q4.x, q4.y, q4.z, q4.w};
            const float kr[8] = {ka.x, ka.y, ka.z, ka.w, kb4.x, kb4.y, kb4.z, kb4.w};
            #pragma unroll
            for (int i = 0; i < 4; ++i)
                #pragma unroll
                for (int j = 0; j < 8; ++j)
                    s[i][j] = fmaf(qr[i], kr[j], s[i][j]);
        }

        // --- online softmax (rows reduced across the 8 mg lanes) ---
        #pragma unroll
        for (int i = 0; i < 4; ++i) {
            float mx = s[i][0];
            #pragma unroll
            for (int j = 1; j < 8; ++j) mx = fmaxf(mx, s[i][j]);
            #pragma unroll
            for (int off = 1; off < 8; off <<= 1)
                mx = fmaxf(mx, __shfl_xor(mx, off, 64));
            const float mn = fmaxf(m_i[i], mx);
            const float alpha = __expf(m_i[i] - mn);
            m_i[i] = mn;
            float rs = 0.f;
            #pragma unroll
            for (int j = 0; j < 8; ++j) { s[i][j] = __expf(s[i][j] - mn); rs += s[i][j]; }
            #pragma unroll
            for (int off = 1; off < 8; off <<= 1) rs += __shfl_xor(rs, off, 64);
            l_i[i] = l_i[i] * alpha + rs;
            #pragma unroll
            for (int j = 0; j < 16; ++j) o_acc[i][j] *= alpha;
            #pragma unroll
            for (int j = 0; j < 8; ++j)
                Plds[wv][mg * 8 + j][qg * 4 + i] = f2bf(s[i][j]);
        }
        // (P write -> P read is same-wave; compiler orders same-array LDS accesses)

        // --- PV: o_acc[i][d'] += P[q][m] * V[m][d'] over this lane's m-slice ---
        #pragma unroll 4
        for (int mm = 0; mm < 16; ++mm) {
            const int m = ms * 16 + mm;
            const uint2 pr = *(const uint2*)&Plds[wv][m][qg * 4];
            float pf[4];
            pf[0] = __uint_as_float(pr.x << 16);
            pf[1] = __uint_as_float(pr.x & 0xffff0000u);
            pf[2] = __uint_as_float(pr.y << 16);
            pf[3] = __uint_as_float(pr.y & 0xffff0000u);
            #pragma unroll
            for (int lb = 0; lb < 4; ++lb) {
                const float4 vv = *(const float4*)&Vlds[m][dg * 16 + ((lb ^ ms) << 2)];
                #pragma unroll
                for (int i = 0; i < 4; ++i) {
                    o_acc[i][lb * 4 + 0] = fmaf(pf[i], vv.x, o_acc[i][lb * 4 + 0]);
                    o_acc[i][lb * 4 + 1] = fmaf(pf[i], vv.y, o_acc[i][lb * 4 + 1]);
                    o_acc[i][lb * 4 + 2] = fmaf(pf[i], vv.z, o_acc[i][lb * 4 + 2]);
                    o_acc[i][lb * 4 + 3] = fmaf(pf[i], vv.w, o_acc[i][lb * 4 + 3]);
                }
            }
        }
    }

    // combine the 4 ms partial sums (lane bits 1,2)
    #pragma unroll
    for (int i = 0; i < 4; ++i)
        #pragma unroll
        for (int j = 0; j < 16; ++j) {
            float v = o_acc[i][j];
            v += __shfl_xor(v, 2, 64);
            v += __shfl_xor(v, 4, 64);
            o_acc[i][j] = v;
        }

    if (ms == 0) {
        #pragma unroll
        for (int i = 0; i < 4; ++i) {
            const float inv = 1.f / l_i[i];
            const int qrow = q0 + wv * 32 + qg * 4 + i;
            float* dst = attn_out + ((size_t)bh * Nx + qrow) * Dx + dg * 16;
            *(float4*)(dst + 0)  = make_float4(o_acc[i][0] * inv,  o_acc[i][1] * inv,
                                               o_acc[i][2] * inv,  o_acc[i][3] * inv);
            *(float4*)(dst + 4)  = make_float4(o_acc[i][4] * inv,  o_acc[i][5] * inv,
                                               o_acc[i][6] * inv,  o_acc[i][7] * inv);
            *(float4*)(dst + 8)  = make_float4(o_acc[i][8] * inv,  o_acc[i][9] * inv,
                                               o_acc[i][10] * inv, o_acc[i][11] * inv);
            *(float4*)(dst + 12) = make_float4(o_acc[i][12] * inv, o_acc[i][13] * inv,
                                               o_acc[i][14] * inv, o_acc[i][15] * inv);
        }
    }
}

// ---------------------------------------------------------------------------
// Kernel 3: proj GEMM + bias + residual + LayerNorm over channels.
// grid (64 n-tiles, 4 b), block 256.  Thread t owns channel o=t for 32 n cols.
// ---------------------------------------------------------------------------
__global__ __launch_bounds__(256, 2) void proj_ln_kernel(
    const float* __restrict__ attn, const float* __restrict__ wp,
    const float* __restrict__ bp, const float* __restrict__ x,
    const float* __restrict__ g, const float* __restrict__ bb,
    float* __restrict__ out)
{
    __shared__ float A[256][36];     // [c][n] attn tile (reused as Y for LN)
    __shared__ float Wl[256][17];    // [o][c-chunk 16]
    __shared__ float red[16][32];
    __shared__ float mv[2][32];
    const int t  = threadIdx.x;
    const int n0 = blockIdx.x * 32;
    const int b  = blockIdx.y;

    // stage A: A[h*32+d][n] = attn[(b*8+h)][n0+n][d]
    #pragma unroll
    for (int it = 0; it < 8; ++it) {
        const int v = t + it * 256;
        const int d4 = (v & 7) * 4, n = (v >> 3) & 31, h = v >> 8;
        const float4 f =
            *(const float4*)&attn[(((size_t)(b * 8 + h)) * Nx + n0 + n) * Dx + d4];
        A[h * 32 + d4 + 0][n] = f.x;
        A[h * 32 + d4 + 1][n] = f.y;
        A[h * 32 + d4 + 2][n] = f.z;
        A[h * 32 + d4 + 3][n] = f.w;
    }

    float acc[32];
    #pragma unroll
    for (int n = 0; n < 32; ++n) acc[n] = 0.f;

    for (int cc = 0; cc < 16; ++cc) {
        __syncthreads();  // also covers initial A staging at cc=0
        #pragma unroll
        for (int it = 0; it < 4; ++it) {
            const int v = t + it * 256;
            const int o = v >> 2, c4 = (v & 3) * 4;
            const float4 f = *(const float4*)&wp[(size_t)o * 256 + cc * 16 + c4];
            Wl[o][c4 + 0] = f.x; Wl[o][c4 + 1] = f.y;
            Wl[o][c4 + 2] = f.z; Wl[o][c4 + 3] = f.w;
        }
        __syncthreads();
        #pragma unroll
        for (int c = 0; c < 16; ++c) {
            const float wv = Wl[t][c];
            #pragma unroll
            for (int n4 = 0; n4 < 8; ++n4) {
                const float4 a = *(const float4*)&A[cc * 16 + c][n4 * 4];
                acc[n4 * 4 + 0] = fmaf(wv, a.x, acc[n4 * 4 + 0]);
                acc[n4 * 4 + 1] = fmaf(wv, a.y, acc[n4 * 4 + 1]);
                acc[n4 * 4 + 2] = fmaf(wv, a.z, acc[n4 * 4 + 2]);
                acc[n4 * 4 + 3] = fmaf(wv, a.w, acc[n4 * 4 + 3]);
            }
        }
    }

    // bias + residual
    const float bpv = bp[t];
    #pragma unroll
    for (int n4 = 0; n4 < 8; ++n4) {
        const float4 xr = *(const float4*)&x[((size_t)b * 256 + t) * Nx + n0 + n4 * 4];
        acc[n4 * 4 + 0] += bpv + xr.x;
        acc[n4 * 4 + 1] += bpv + xr.y;
        acc[n4 * 4 + 2] += bpv + xr.z;
        acc[n4 * 4 + 3] += bpv + xr.w;
    }

    __syncthreads();                 // done reading A as attn tile
    #pragma unroll
    for (int n = 0; n < 32; ++n) A[t][n] = acc[n];   // Y[o][n]
    __syncthreads();

    {
        const int nr = t & 31, og = t >> 5;
        float sm = 0.f, sq = 0.f;
        #pragma unroll 8
        for (int oi = 0; oi < 32; ++oi) {
            const float vy = A[og * 32 + oi][nr];
            sm += vy; sq += vy * vy;
        }
        red[og][nr] = sm;
        red[8 + og][nr] = sq;
    }
    __syncthreads();
    if (t < 32) {
        float S = 0.f, Q = 0.f;
        #pragma unroll
        for (int og = 0; og < 8; ++og) { S += red[og][t]; Q += red[8 + og][t]; }
        const float mu  = S * (1.f / 256.f);
        const float var = Q * (1.f / 256.f) - mu * mu;
        mv[0][t] = mu;
        mv[1][t] = rsqrtf(var + 1e-5f);
    }
    __syncthreads();

    const float gv = g[t], bv2 = bb[t];
    float* dst = &out[((size_t)b * 256 + t) * Nx + n0];
    #pragma unroll
    for (int n4 = 0; n4 < 8; ++n4) {
        float4 o4;
        o4.x = (acc[n4 * 4 + 0] - mv[0][n4 * 4 + 0]) * mv[1][n4 * 4 + 0] * gv + bv2;
        o4.y = (acc[n4 * 4 + 1] - mv[0][n4 * 4 + 1]) * mv[1][n4 * 4 + 1] * gv + bv2;
        o4.z = (acc[n4 * 4 + 2] - mv[0][n4 * 4 + 2]) * mv[1][n4 * 4 + 2] * gv + bv2;
        o4.w = (acc[n4 * 4 + 3] - mv[0][n4 * 4 + 3]) * mv[1][n4 * 4 + 3] * gv + bv2;
        *(float4*)(dst + n4 * 4) = o4;
    }
}

// ---------------------------------------------------------------------------
extern "C" void kernel_launch(void* const* d_in, const int* in_sizes, int n_in,
                              void* d_out, int out_size, void* d_ws, size_t ws_size,
                              hipStream_t stream) {
    (void)in_sizes; (void)n_in; (void)out_size; (void)ws_size;
    const float* x      = (const float*)d_in[0];
    const float* w_qkv  = (const float*)d_in[1];
    const float* b_qkv  = (const float*)d_in[2];
    const float* w_proj = (const float*)d_in[3];
    const float* b_proj = (const float*)d_in[4];
    const float* ln_g   = (const float*)d_in[5];
    const float* ln_b   = (const float*)d_in[6];
    float* out = (float*)d_out;

    // workspace: qkv [B][768][N] fp32 (24 MB), attn [B*H][N][D] fp32 (8 MB)
    float* qkv  = (float*)d_ws;
    float* attn = (float*)((char*)d_ws + (size_t)Bx * 768 * Nx * sizeof(float));

    qkv_kernel<<<dim3(12, 16, 4), 256, 0, stream>>>(x, w_qkv, b_qkv, qkv);
    attn_kernel<<<dim3(16, 32), 256, 0, stream>>>(qkv, attn);
    proj_ln_kernel<<<dim3(64, 4), 256, 0, stream>>>(attn, w_proj, b_proj, x,
                                                    ln_g, ln_b, out);
}

// Round 3
// 238.464 us; speedup vs baseline: 1.7666x; 1.7666x over previous
//
#include <hip/hip_runtime.h>
#include <hip/hip_bf16.h>

// Problem constants (fixed by reference): B=4, C=256, N=2048, H=8, D=32
#define Bx 4
#define Cx 256
#define Nx 2048
#define Hx 8
#define Dx 32

typedef __attribute__((ext_vector_type(8))) short bf16x8;   // 8 bf16 (4 VGPRs)
typedef __attribute__((ext_vector_type(4))) float f32x4;

// attention scale folded with log2(e) so softmax can use native exp2:
// (1/sqrt(32)) * 1.4426950408889634
#define QSCALE 0.25503494f

static __device__ __forceinline__ unsigned short f2bf(float f) {
    // round-to-nearest-even bf16
    unsigned int u = __float_as_uint(f);
    u += 0x7fffu + ((u >> 16) & 1u);
    return (unsigned short)(u >> 16);
}

// ---------------------------------------------------------------------------
// Kernel 1: QKV projection (fp32 GEMM core), epilogue emits bf16 in
// MFMA-friendly layouts:
//   Qb[bh][n][d] (pre-scaled by QSCALE), Kb[bh][n][d], Vb[bh][d][n]
// grid (12 o-tiles, 16 n-tiles, 4 b), block 256.  Tile: 64 o x 128 n.
// blockIdx.x: 0-3 -> Q, 4-7 -> K, 8-11 -> V (64 | 256 so regions are clean).
// ---------------------------------------------------------------------------
__global__ __launch_bounds__(256, 3) void qkv_kernel(
    const float* __restrict__ x, const float* __restrict__ w,
    const float* __restrict__ bias,
    unsigned short* __restrict__ Qb, unsigned short* __restrict__ Kb,
    unsigned short* __restrict__ Vb)
{
    __shared__ float Wl[64][68];    // [c][o]  (transposed W tile)
    __shared__ float Xl[64][132];   // [c][n]
    const int t  = threadIdx.x;
    const int o0 = blockIdx.x * 64;
    const int n0 = blockIdx.y * 128;
    const int b  = blockIdx.z;
    const int og = t >> 4, ng = t & 15;   // 16x16 thread grid, 4o x 8n each

    float acc[4][8];
    #pragma unroll
    for (int i = 0; i < 4; ++i)
        #pragma unroll
        for (int j = 0; j < 8; ++j) acc[i][j] = 0.f;

    for (int cc = 0; cc < Cx; cc += 64) {
        __syncthreads();
        #pragma unroll
        for (int it = 0; it < 4; ++it) {
            const int v = t + it * 256;
            const int oi = v >> 4, c4 = (v & 15) * 4;
            const float4 f = *(const float4*)&w[(size_t)(o0 + oi) * Cx + cc + c4];
            Wl[c4 + 0][oi] = f.x; Wl[c4 + 1][oi] = f.y;
            Wl[c4 + 2][oi] = f.z; Wl[c4 + 3][oi] = f.w;
        }
        #pragma unroll
        for (int it = 0; it < 8; ++it) {
            const int v = t + it * 256;
            const int ci = v >> 5, n4 = (v & 31) * 4;
            *(float4*)&Xl[ci][n4] =
                *(const float4*)&x[((size_t)b * Cx + cc + ci) * Nx + n0 + n4];
        }
        __syncthreads();
        #pragma unroll 8
        for (int c = 0; c < 64; ++c) {
            const float4 w4 = *(const float4*)&Wl[c][og * 4];
            const float4 xa = *(const float4*)&Xl[c][ng * 8];
            const float4 xb = *(const float4*)&Xl[c][ng * 8 + 4];
            const float wr[4] = {w4.x, w4.y, w4.z, w4.w};
            const float xr[8] = {xa.x, xa.y, xa.z, xa.w, xb.x, xb.y, xb.z, xb.w};
            #pragma unroll
            for (int i = 0; i < 4; ++i)
                #pragma unroll
                for (int j = 0; j < 8; ++j)
                    acc[i][j] = fmaf(wr[i], xr[j], acc[i][j]);
        }
    }

    // epilogue: bias, (scale), convert to bf16, write attention layouts
    const int region = blockIdx.x >> 2;            // 0=Q, 1=K, 2=V
    const int oc = (blockIdx.x & 3) * 64 + og * 4; // channel within 256, mult of 4
    const int h = oc >> 5, d0 = oc & 31;
    const int bh = b * 8 + h;

    float vals[4][8];
    #pragma unroll
    for (int i = 0; i < 4; ++i) {
        const float bv = bias[o0 + og * 4 + i];
        #pragma unroll
        for (int j = 0; j < 8; ++j) {
            float v = acc[i][j] + bv;
            if (region == 0) v *= QSCALE;
            vals[i][j] = v;
        }
    }

    if (region < 2) {
        unsigned short* dst = (region == 0 ? Qb : Kb);
        #pragma unroll
        for (int j = 0; j < 8; ++j) {
            const int n = n0 + ng * 8 + j;
            ushort4 w4;
            w4.x = f2bf(vals[0][j]); w4.y = f2bf(vals[1][j]);
            w4.z = f2bf(vals[2][j]); w4.w = f2bf(vals[3][j]);
            *(ushort4*)&dst[(((size_t)bh * Nx) + n) * Dx + d0] = w4;
        }
    } else {
        #pragma unroll
        for (int i = 0; i < 4; ++i) {
            uint4 pk;
            pk.x = (unsigned int)f2bf(vals[i][0]) | ((unsigned int)f2bf(vals[i][1]) << 16);
            pk.y = (unsigned int)f2bf(vals[i][2]) | ((unsigned int)f2bf(vals[i][3]) << 16);
            pk.z = (unsigned int)f2bf(vals[i][4]) | ((unsigned int)f2bf(vals[i][5]) << 16);
            pk.w = (unsigned int)f2bf(vals[i][6]) | ((unsigned int)f2bf(vals[i][7]) << 16);
            *(uint4*)&Vb[(((size_t)bh * Dx) + d0 + i) * Nx + n0 + ng * 8] = pk;
        }
    }
}

// ---------------------------------------------------------------------------
// Kernel 2: MFMA flash attention.
// grid (16, 32 bh), block 256 = 4 independent waves; wave owns 32 q rows.
// Swapped scheme: S^T = K·Q^T  (16x16x32 bf16 MFMA, one per tile, K-dim = D)
//                 O^T = V^T·P^T (P redistributed via per-wave LDS, bf16-packed)
// C/D layout (verified): col = lane&15, row = (lane>>4)*4 + reg.
// A row = lane&15, B col = lane&15; k element j pairs identically for A and B,
// so the k-reduction is correct independent of HW's internal k ordering.
// ---------------------------------------------------------------------------
__global__ __launch_bounds__(256) void attn_kernel(
    const unsigned short* __restrict__ Qb, const unsigned short* __restrict__ Kb,
    const unsigned short* __restrict__ Vb, float* __restrict__ attn_out)
{
    __shared__ unsigned int Plds[4][32][36];   // per-wave P (bf16-pair packed)

    const int t  = threadIdx.x;
    const int wv = t >> 6, l = t & 63;
    const int g  = l >> 4, c = l & 15;
    const int q0 = blockIdx.x * 128 + wv * 32;
    const int bh = blockIdx.y;

    const unsigned short* Qp = Qb + (size_t)bh * Nx * Dx;
    const unsigned short* Kp = Kb + (size_t)bh * Nx * Dx;
    const unsigned short* Vp = Vb + (size_t)bh * Dx * Nx;
    unsigned int* pl = &Plds[wv][0][0];        // [32 kv-pair][36] u32

    // Q fragments: lane holds Q[q0+qt*16+c][g*8 .. g*8+8)
    bf16x8 qf[2];
    #pragma unroll
    for (int qt = 0; qt < 2; ++qt)
        qf[qt] = *(const bf16x8*)&Qp[(size_t)(q0 + qt * 16 + c) * Dx + g * 8];

    f32x4 oacc[2][2];                          // [dt][qt]
    #pragma unroll
    for (int i = 0; i < 2; ++i)
        #pragma unroll
        for (int j = 0; j < 2; ++j)
            oacc[i][j] = (f32x4){0.f, 0.f, 0.f, 0.f};
    float m_i[2] = {-3.0e38f, -3.0e38f};
    float l_i[2] = {0.f, 0.f};
    const f32x4 zacc = (f32x4){0.f, 0.f, 0.f, 0.f};

    for (int kv0 = 0; kv0 < Nx; kv0 += 64) {
        // K fragments (A of S^T): K[kv0+ct*16+c][g*8..+8)
        bf16x8 kf[4];
        #pragma unroll
        for (int ct = 0; ct < 4; ++ct)
            kf[ct] = *(const bf16x8*)&Kp[(size_t)(kv0 + ct * 16 + c) * Dx + g * 8];
        // V fragments (A of O^T): V^T[dt*16+c][kv0+kc*32+g*8..+8)
        bf16x8 vf[2][2];
        #pragma unroll
        for (int dt = 0; dt < 2; ++dt)
            #pragma unroll
            for (int kc = 0; kc < 2; ++kc)
                vf[dt][kc] = *(const bf16x8*)
                    &Vp[(size_t)(dt * 16 + c) * Nx + kv0 + kc * 32 + g * 8];

        // --- S^T = K·Q^T : 8 MFMAs ---
        f32x4 sacc[4][2];
        #pragma unroll
        for (int ct = 0; ct < 4; ++ct) {
            sacc[ct][0] = __builtin_amdgcn_mfma_f32_16x16x32_bf16(kf[ct], qf[0], zacc, 0, 0, 0);
            sacc[ct][1] = __builtin_amdgcn_mfma_f32_16x16x32_bf16(kf[ct], qf[1], zacc, 0, 0, 0);
        }

        // --- online softmax (exp2 domain; Q pre-scaled by QSCALE) ---
        float alpha_[2];
        #pragma unroll
        for (int qt = 0; qt < 2; ++qt) {
            float mx = -3.0e38f;
            #pragma unroll
            for (int ct = 0; ct < 4; ++ct)
                #pragma unroll
                for (int r = 0; r < 4; ++r) mx = fmaxf(mx, sacc[ct][qt][r]);
            mx = fmaxf(mx, __shfl_xor(mx, 16, 64));
            mx = fmaxf(mx, __shfl_xor(mx, 32, 64));
            const float mnew = fmaxf(m_i[qt], mx);
            alpha_[qt] = exp2f(m_i[qt] - mnew);
            m_i[qt] = mnew;
            float rs = 0.f;
            #pragma unroll
            for (int ct = 0; ct < 4; ++ct) {
                float p[4];
                #pragma unroll
                for (int r = 0; r < 4; ++r) {
                    p[r] = exp2f(sacc[ct][qt][r] - mnew);
                    rs += p[r];
                }
                // pack kv pairs (even -> low half, odd -> high half), truncation
                const unsigned int w0 = (__float_as_uint(p[0]) >> 16) |
                                        (__float_as_uint(p[1]) & 0xffff0000u);
                const unsigned int w1 = (__float_as_uint(p[2]) >> 16) |
                                        (__float_as_uint(p[3]) & 0xffff0000u);
                pl[(ct * 8 + g * 2 + 0) * 36 + qt * 16 + c] = w0;
                pl[(ct * 8 + g * 2 + 1) * 36 + qt * 16 + c] = w1;
            }
            rs += __shfl_xor(rs, 16, 64);
            rs += __shfl_xor(rs, 32, 64);
            l_i[qt] = l_i[qt] * alpha_[qt] + rs;
        }
        // rescale O by alpha
        #pragma unroll
        for (int dt = 0; dt < 2; ++dt)
            #pragma unroll
            for (int qt = 0; qt < 2; ++qt)
                #pragma unroll
                for (int r = 0; r < 4; ++r)
                    oacc[dt][qt][r] *= alpha_[qt];

        // --- O^T += V^T·P^T : 8 MFMAs (B frag read back per-wave from LDS) ---
        #pragma unroll
        for (int qt = 0; qt < 2; ++qt)
            #pragma unroll
            for (int kc = 0; kc < 2; ++kc) {
                union { unsigned int u[4]; bf16x8 v; } bw;
                #pragma unroll
                for (int widx = 0; widx < 4; ++widx)
                    bw.u[widx] = pl[(kc * 16 + g * 4 + widx) * 36 + qt * 16 + c];
                oacc[0][qt] = __builtin_amdgcn_mfma_f32_16x16x32_bf16(vf[0][kc], bw.v, oacc[0][qt], 0, 0, 0);
                oacc[1][qt] = __builtin_amdgcn_mfma_f32_16x16x32_bf16(vf[1][kc], bw.v, oacc[1][qt], 0, 0, 0);
            }
    }

    // epilogue: O = O^T / l, store fp32 [bh][n][d]
    #pragma unroll
    for (int qt = 0; qt < 2; ++qt) {
        const float inv = 1.f / l_i[qt];
        #pragma unroll
        for (int dt = 0; dt < 2; ++dt) {
            f32x4 ov = oacc[dt][qt];
            ov[0] *= inv; ov[1] *= inv; ov[2] *= inv; ov[3] *= inv;
            *(f32x4*)&attn_out[((size_t)bh * Nx + q0 + qt * 16 + c) * Dx
                               + dt * 16 + g * 4] = ov;
        }
    }
}

// ---------------------------------------------------------------------------
// Kernel 3: proj GEMM + bias + residual + LayerNorm over channels. (unchanged)
// grid (64 n-tiles, 4 b), block 256.  Thread t owns channel o=t for 32 n cols.
// ---------------------------------------------------------------------------
__global__ __launch_bounds__(256, 2) void proj_ln_kernel(
    const float* __restrict__ attn, const float* __restrict__ wp,
    const float* __restrict__ bp, const float* __restrict__ x,
    const float* __restrict__ g, const float* __restrict__ bb,
    float* __restrict__ out)
{
    __shared__ float A[256][36];     // [c][n] attn tile (reused as Y for LN)
    __shared__ float Wl[256][17];    // [o][c-chunk 16]
    __shared__ float red[16][32];
    __shared__ float mv[2][32];
    const int t  = threadIdx.x;
    const int n0 = blockIdx.x * 32;
    const int b  = blockIdx.y;

    #pragma unroll
    for (int it = 0; it < 8; ++it) {
        const int v = t + it * 256;
        const int d4 = (v & 7) * 4, n = (v >> 3) & 31, h = v >> 8;
        const float4 f =
            *(const float4*)&attn[(((size_t)(b * 8 + h)) * Nx + n0 + n) * Dx + d4];
        A[h * 32 + d4 + 0][n] = f.x;
        A[h * 32 + d4 + 1][n] = f.y;
        A[h * 32 + d4 + 2][n] = f.z;
        A[h * 32 + d4 + 3][n] = f.w;
    }

    float acc[32];
    #pragma unroll
    for (int n = 0; n < 32; ++n) acc[n] = 0.f;

    for (int cc = 0; cc < 16; ++cc) {
        __syncthreads();
        #pragma unroll
        for (int it = 0; it < 4; ++it) {
            const int v = t + it * 256;
            const int o = v >> 2, c4 = (v & 3) * 4;
            const float4 f = *(const float4*)&wp[(size_t)o * 256 + cc * 16 + c4];
            Wl[o][c4 + 0] = f.x; Wl[o][c4 + 1] = f.y;
            Wl[o][c4 + 2] = f.z; Wl[o][c4 + 3] = f.w;
        }
        __syncthreads();
        #pragma unroll
        for (int c = 0; c < 16; ++c) {
            const float wv = Wl[t][c];
            #pragma unroll
            for (int n4 = 0; n4 < 8; ++n4) {
                const float4 a = *(const float4*)&A[cc * 16 + c][n4 * 4];
                acc[n4 * 4 + 0] = fmaf(wv, a.x, acc[n4 * 4 + 0]);
                acc[n4 * 4 + 1] = fmaf(wv, a.y, acc[n4 * 4 + 1]);
                acc[n4 * 4 + 2] = fmaf(wv, a.z, acc[n4 * 4 + 2]);
                acc[n4 * 4 + 3] = fmaf(wv, a.w, acc[n4 * 4 + 3]);
            }
        }
    }

    const float bpv = bp[t];
    #pragma unroll
    for (int n4 = 0; n4 < 8; ++n4) {
        const float4 xr = *(const float4*)&x[((size_t)b * 256 + t) * Nx + n0 + n4 * 4];
        acc[n4 * 4 + 0] += bpv + xr.x;
        acc[n4 * 4 + 1] += bpv + xr.y;
        acc[n4 * 4 + 2] += bpv + xr.z;
        acc[n4 * 4 + 3] += bpv + xr.w;
    }

    __syncthreads();
    #pragma unroll
    for (int n = 0; n < 32; ++n) A[t][n] = acc[n];
    __syncthreads();

    {
        const int nr = t & 31, og = t >> 5;
        float sm = 0.f, sq = 0.f;
        #pragma unroll 8
        for (int oi = 0; oi < 32; ++oi) {
            const float vy = A[og * 32 + oi][nr];
            sm += vy; sq += vy * vy;
        }
        red[og][nr] = sm;
        red[8 + og][nr] = sq;
    }
    __syncthreads();
    if (t < 32) {
        float S = 0.f, Q = 0.f;
        #pragma unroll
        for (int og = 0; og < 8; ++og) { S += red[og][t]; Q += red[8 + og][t]; }
        const float mu  = S * (1.f / 256.f);
        const float var = Q * (1.f / 256.f) - mu * mu;
        mv[0][t] = mu;
        mv[1][t] = rsqrtf(var + 1e-5f);
    }
    __syncthreads();

    const float gv = g[t], bv2 = bb[t];
    float* dst = &out[((size_t)b * 256 + t) * Nx + n0];
    #pragma unroll
    for (int n4 = 0; n4 < 8; ++n4) {
        float4 o4;
        o4.x = (acc[n4 * 4 + 0] - mv[0][n4 * 4 + 0]) * mv[1][n4 * 4 + 0] * gv + bv2;
        o4.y = (acc[n4 * 4 + 1] - mv[0][n4 * 4 + 1]) * mv[1][n4 * 4 + 1] * gv + bv2;
        o4.z = (acc[n4 * 4 + 2] - mv[0][n4 * 4 + 2]) * mv[1][n4 * 4 + 2] * gv + bv2;
        o4.w = (acc[n4 * 4 + 3] - mv[0][n4 * 4 + 3]) * mv[1][n4 * 4 + 3] * gv + bv2;
        *(float4*)(dst + n4 * 4) = o4;
    }
}

// ---------------------------------------------------------------------------
extern "C" void kernel_launch(void* const* d_in, const int* in_sizes, int n_in,
                              void* d_out, int out_size, void* d_ws, size_t ws_size,
                              hipStream_t stream) {
    (void)in_sizes; (void)n_in; (void)out_size; (void)ws_size;
    const float* x      = (const float*)d_in[0];
    const float* w_qkv  = (const float*)d_in[1];
    const float* b_qkv  = (const float*)d_in[2];
    const float* w_proj = (const float*)d_in[3];
    const float* b_proj = (const float*)d_in[4];
    const float* ln_g   = (const float*)d_in[5];
    const float* ln_b   = (const float*)d_in[6];
    float* out = (float*)d_out;

    // workspace: Qb/Kb/Vb bf16 4MB each, attn fp32 8MB  => 20MB total
    unsigned short* Qb = (unsigned short*)d_ws;
    unsigned short* Kb = Qb + (size_t)Bx * Hx * Nx * Dx;
    unsigned short* Vb = Kb + (size_t)Bx * Hx * Nx * Dx;
    float* attn = (float*)((char*)d_ws + (size_t)12 * 1024 * 1024);

    qkv_kernel<<<dim3(12, 16, 4), 256, 0, stream>>>(x, w_qkv, b_qkv, Qb, Kb, Vb);
    attn_kernel<<<dim3(16, 32), 256, 0, stream>>>(Qb, Kb, Vb, attn);
    proj_ln_kernel<<<dim3(64, 4), 256, 0, stream>>>(attn, w_proj, b_proj, x,
                                                    ln_g, ln_b, out);
}

// Round 4
// 219.558 us; speedup vs baseline: 1.9187x; 1.0861x over previous
//
#include <hip/hip_runtime.h>
#include <hip/hip_bf16.h>

// Problem constants (fixed by reference): B=4, C=256, N=2048, H=8, D=32
#define Bx 4
#define Cx 256
#define Nx 2048
#define Hx 8
#define Dx 32

typedef __attribute__((ext_vector_type(8))) short bf16x8;   // 8 bf16 (4 VGPRs)
typedef __attribute__((ext_vector_type(4))) float f32x4;

// attention scale folded with log2(e) so softmax can use native exp2:
// (1/sqrt(32)) * 1.4426950408889634
#define QSCALE 0.25503494f

static __device__ __forceinline__ unsigned short f2bf(float f) {
    // round-to-nearest-even bf16
    unsigned int u = __float_as_uint(f);
    u += 0x7fffu + ((u >> 16) & 1u);
    return (unsigned short)(u >> 16);
}

// ---------------------------------------------------------------------------
// Kernel 1: QKV projection (fp32 GEMM core), epilogue emits bf16 in
// MFMA-friendly layouts:
//   Qb[bh][n][d] (pre-scaled by QSCALE), Kb[bh][n][d], Vb[bh][d][n]
// grid (12 o-tiles, 16 n-tiles, 4 b), block 256.  Tile: 64 o x 128 n.
// blockIdx.x: 0-3 -> Q, 4-7 -> K, 8-11 -> V (64 | 256 so regions are clean).
// ---------------------------------------------------------------------------
__global__ __launch_bounds__(256, 3) void qkv_kernel(
    const float* __restrict__ x, const float* __restrict__ w,
    const float* __restrict__ bias,
    unsigned short* __restrict__ Qb, unsigned short* __restrict__ Kb,
    unsigned short* __restrict__ Vb)
{
    __shared__ float Wl[64][68];    // [c][o]  (transposed W tile)
    __shared__ float Xl[64][132];   // [c][n]
    const int t  = threadIdx.x;
    const int o0 = blockIdx.x * 64;
    const int n0 = blockIdx.y * 128;
    const int b  = blockIdx.z;
    const int og = t >> 4, ng = t & 15;   // 16x16 thread grid, 4o x 8n each

    float acc[4][8];
    #pragma unroll
    for (int i = 0; i < 4; ++i)
        #pragma unroll
        for (int j = 0; j < 8; ++j) acc[i][j] = 0.f;

    for (int cc = 0; cc < Cx; cc += 64) {
        __syncthreads();
        #pragma unroll
        for (int it = 0; it < 4; ++it) {
            const int v = t + it * 256;
            const int oi = v >> 4, c4 = (v & 15) * 4;
            const float4 f = *(const float4*)&w[(size_t)(o0 + oi) * Cx + cc + c4];
            Wl[c4 + 0][oi] = f.x; Wl[c4 + 1][oi] = f.y;
            Wl[c4 + 2][oi] = f.z; Wl[c4 + 3][oi] = f.w;
        }
        #pragma unroll
        for (int it = 0; it < 8; ++it) {
            const int v = t + it * 256;
            const int ci = v >> 5, n4 = (v & 31) * 4;
            *(float4*)&Xl[ci][n4] =
                *(const float4*)&x[((size_t)b * Cx + cc + ci) * Nx + n0 + n4];
        }
        __syncthreads();
        #pragma unroll 8
        for (int c = 0; c < 64; ++c) {
            const float4 w4 = *(const float4*)&Wl[c][og * 4];
            const float4 xa = *(const float4*)&Xl[c][ng * 8];
            const float4 xb = *(const float4*)&Xl[c][ng * 8 + 4];
            const float wr[4] = {w4.x, w4.y, w4.z, w4.w};
            const float xr[8] = {xa.x, xa.y, xa.z, xa.w, xb.x, xb.y, xb.z, xb.w};
            #pragma unroll
            for (int i = 0; i < 4; ++i)
                #pragma unroll
                for (int j = 0; j < 8; ++j)
                    acc[i][j] = fmaf(wr[i], xr[j], acc[i][j]);
        }
    }

    // epilogue: bias, (scale), convert to bf16, write attention layouts
    const int region = blockIdx.x >> 2;            // 0=Q, 1=K, 2=V
    const int oc = (blockIdx.x & 3) * 64 + og * 4; // channel within 256, mult of 4
    const int h = oc >> 5, d0 = oc & 31;
    const int bh = b * 8 + h;

    float vals[4][8];
    #pragma unroll
    for (int i = 0; i < 4; ++i) {
        const float bv = bias[o0 + og * 4 + i];
        #pragma unroll
        for (int j = 0; j < 8; ++j) {
            float v = acc[i][j] + bv;
            if (region == 0) v *= QSCALE;
            vals[i][j] = v;
        }
    }

    if (region < 2) {
        unsigned short* dst = (region == 0 ? Qb : Kb);
        #pragma unroll
        for (int j = 0; j < 8; ++j) {
            const int n = n0 + ng * 8 + j;
            ushort4 w4;
            w4.x = f2bf(vals[0][j]); w4.y = f2bf(vals[1][j]);
            w4.z = f2bf(vals[2][j]); w4.w = f2bf(vals[3][j]);
            *(ushort4*)&dst[(((size_t)bh * Nx) + n) * Dx + d0] = w4;
        }
    } else {
        #pragma unroll
        for (int i = 0; i < 4; ++i) {
            uint4 pk;
            pk.x = (unsigned int)f2bf(vals[i][0]) | ((unsigned int)f2bf(vals[i][1]) << 16);
            pk.y = (unsigned int)f2bf(vals[i][2]) | ((unsigned int)f2bf(vals[i][3]) << 16);
            pk.z = (unsigned int)f2bf(vals[i][4]) | ((unsigned int)f2bf(vals[i][5]) << 16);
            pk.w = (unsigned int)f2bf(vals[i][6]) | ((unsigned int)f2bf(vals[i][7]) << 16);
            *(uint4*)&Vb[(((size_t)bh * Dx) + d0 + i) * Nx + n0 + ng * 8] = pk;
        }
    }
}

// ---------------------------------------------------------------------------
// Kernel 2: MFMA flash attention, KV-split by blockIdx.z (flash-decoding).
// grid (16, 32 bh, 2 z), block 256 = 4 independent waves; wave owns 32 q rows
// over kv range [z*1024, z*1024+1024).  Outputs: unnormalized partial O^T and
// per-row (m, l) float2 for the fused merge in proj_ln.
// Swapped scheme: S^T = K·Q^T, O^T = V^T·P^T (P via per-wave LDS, bf16-packed).
// C/D layout: col = lane&15, row = (lane>>4)*4 + reg.
// Defer-max (T13): keep old running max while tile max grows <= 8 (log2
// domain, p <= 2^8) -> skip alpha-exp2 and O-rescale on most tiles.
// ---------------------------------------------------------------------------
__global__ __launch_bounds__(256) void attn_kernel(
    const unsigned short* __restrict__ Qb, const unsigned short* __restrict__ Kb,
    const unsigned short* __restrict__ Vb, float* __restrict__ Opart,
    float2* __restrict__ ML)
{
    __shared__ unsigned int Plds[4][32][36];   // per-wave P (bf16-pair packed)

    const int t  = threadIdx.x;
    const int wv = t >> 6, l = t & 63;
    const int g  = l >> 4, c = l & 15;
    const int q0 = blockIdx.x * 128 + wv * 32;
    const int bh = blockIdx.y;
    const int z  = blockIdx.z;

    const unsigned short* Qp = Qb + (size_t)bh * Nx * Dx;
    const unsigned short* Kp = Kb + (size_t)bh * Nx * Dx;
    const unsigned short* Vp = Vb + (size_t)bh * Dx * Nx;
    unsigned int* pl = &Plds[wv][0][0];        // [32 kv-pair][36] u32

    // Q fragments: lane holds Q[q0+qt*16+c][g*8 .. g*8+8)
    bf16x8 qf[2];
    #pragma unroll
    for (int qt = 0; qt < 2; ++qt)
        qf[qt] = *(const bf16x8*)&Qp[(size_t)(q0 + qt * 16 + c) * Dx + g * 8];

    f32x4 oacc[2][2];                          // [dt][qt]
    #pragma unroll
    for (int i = 0; i < 2; ++i)
        #pragma unroll
        for (int j = 0; j < 2; ++j)
            oacc[i][j] = (f32x4){0.f, 0.f, 0.f, 0.f};
    float m_i[2] = {-3.0e38f, -3.0e38f};
    float l_i[2] = {0.f, 0.f};
    const f32x4 zacc = (f32x4){0.f, 0.f, 0.f, 0.f};

    const int kv_beg = z * (Nx / 2), kv_end = kv_beg + (Nx / 2);
    for (int kv0 = kv_beg; kv0 < kv_end; kv0 += 64) {
        // K fragments (A of S^T): K[kv0+ct*16+c][g*8..+8)
        bf16x8 kf[4];
        #pragma unroll
        for (int ct = 0; ct < 4; ++ct)
            kf[ct] = *(const bf16x8*)&Kp[(size_t)(kv0 + ct * 16 + c) * Dx + g * 8];
        // V fragments (A of O^T): V^T[dt*16+c][kv0+kc*32+g*8..+8)
        bf16x8 vf[2][2];
        #pragma unroll
        for (int dt = 0; dt < 2; ++dt)
            #pragma unroll
            for (int kc = 0; kc < 2; ++kc)
                vf[dt][kc] = *(const bf16x8*)
                    &Vp[(size_t)(dt * 16 + c) * Nx + kv0 + kc * 32 + g * 8];

        // --- S^T = K·Q^T : 8 MFMAs ---
        f32x4 sacc[4][2];
        #pragma unroll
        for (int ct = 0; ct < 4; ++ct) {
            sacc[ct][0] = __builtin_amdgcn_mfma_f32_16x16x32_bf16(kf[ct], qf[0], zacc, 0, 0, 0);
            sacc[ct][1] = __builtin_amdgcn_mfma_f32_16x16x32_bf16(kf[ct], qf[1], zacc, 0, 0, 0);
        }

        // --- online softmax (exp2 domain; Q pre-scaled by QSCALE) ---
        #pragma unroll
        for (int qt = 0; qt < 2; ++qt) {
            float mx = -3.0e38f;
            #pragma unroll
            for (int ct = 0; ct < 4; ++ct)
                #pragma unroll
                for (int r = 0; r < 4; ++r) mx = fmaxf(mx, sacc[ct][qt][r]);
            mx = fmaxf(mx, __shfl_xor(mx, 16, 64));
            mx = fmaxf(mx, __shfl_xor(mx, 32, 64));
            // defer-max: only rescale when tile max outgrows running max by >8
            if (mx > m_i[qt] + 8.f) {          // wave-uniform branch
                const float aq = exp2f(m_i[qt] - mx);
                m_i[qt] = mx;
                l_i[qt] *= aq;
                #pragma unroll
                for (int dt = 0; dt < 2; ++dt)
                    #pragma unroll
                    for (int r = 0; r < 4; ++r) oacc[dt][qt][r] *= aq;
            }
            const float mcur = m_i[qt];
            float rs = 0.f;
            #pragma unroll
            for (int ct = 0; ct < 4; ++ct) {
                float p[4];
                #pragma unroll
                for (int r = 0; r < 4; ++r) {
                    p[r] = exp2f(sacc[ct][qt][r] - mcur);
                    rs += p[r];
                }
                // pack kv pairs (even -> low half, odd -> high half), truncation
                const unsigned int w0 = (__float_as_uint(p[0]) >> 16) |
                                        (__float_as_uint(p[1]) & 0xffff0000u);
                const unsigned int w1 = (__float_as_uint(p[2]) >> 16) |
                                        (__float_as_uint(p[3]) & 0xffff0000u);
                pl[(ct * 8 + g * 2 + 0) * 36 + qt * 16 + c] = w0;
                pl[(ct * 8 + g * 2 + 1) * 36 + qt * 16 + c] = w1;
            }
            rs += __shfl_xor(rs, 16, 64);
            rs += __shfl_xor(rs, 32, 64);
            l_i[qt] += rs;
        }

        // --- O^T += V^T·P^T : 8 MFMAs (B frag read back per-wave from LDS) ---
        #pragma unroll
        for (int qt = 0; qt < 2; ++qt)
            #pragma unroll
            for (int kc = 0; kc < 2; ++kc) {
                union { unsigned int u[4]; bf16x8 v; } bw;
                #pragma unroll
                for (int widx = 0; widx < 4; ++widx)
                    bw.u[widx] = pl[(kc * 16 + g * 4 + widx) * 36 + qt * 16 + c];
                oacc[0][qt] = __builtin_amdgcn_mfma_f32_16x16x32_bf16(vf[0][kc], bw.v, oacc[0][qt], 0, 0, 0);
                oacc[1][qt] = __builtin_amdgcn_mfma_f32_16x16x32_bf16(vf[1][kc], bw.v, oacc[1][qt], 0, 0, 0);
            }
    }

    // epilogue: store unnormalized partial O^T + (m,l), fp32 [z][bh][n][d]
    float* Op = Opart + ((size_t)(z * 32 + bh)) * Nx * Dx;
    float2* Mlp = ML + ((size_t)(z * 32 + bh)) * Nx;
    #pragma unroll
    for (int qt = 0; qt < 2; ++qt) {
        const int q = q0 + qt * 16 + c;
        if (g == 0) Mlp[q] = make_float2(m_i[qt], l_i[qt]);
        #pragma unroll
        for (int dt = 0; dt < 2; ++dt)
            *(f32x4*)&Op[(size_t)q * Dx + dt * 16 + g * 4] = oacc[dt][qt];
    }
}

// ---------------------------------------------------------------------------
// Kernel 3: fused KV-split merge + proj GEMM + bias + residual + LayerNorm.
// grid (64 n-tiles, 4 b), block 256.  Thread t owns channel o=t for 32 n cols.
// ---------------------------------------------------------------------------
__global__ __launch_bounds__(256, 2) void proj_ln_kernel(
    const float* __restrict__ Opart, const float2* __restrict__ ML,
    const float* __restrict__ wp,
    const float* __restrict__ bp, const float* __restrict__ x,
    const float* __restrict__ g, const float* __restrict__ bb,
    float* __restrict__ out)
{
    __shared__ float A[256][36];     // [c][n] merged attn tile (reused for LN)
    __shared__ float Wl[256][17];    // [o][c-chunk 16]
    __shared__ float red[16][32];
    __shared__ float mv[2][32];
    const int t  = threadIdx.x;
    const int n0 = blockIdx.x * 32;
    const int b  = blockIdx.y;

    // stage A with on-the-fly merge of the two KV halves
    #pragma unroll
    for (int it = 0; it < 8; ++it) {
        const int v = t + it * 256;
        const int d4 = (v & 7) * 4, n = (v >> 3) & 31, h = v >> 8;
        const int bh = b * 8 + h;
        const size_t base = ((size_t)bh * Nx + n0 + n) * Dx + d4;
        const float4 f0 = *(const float4*)&Opart[base];
        const float4 f1 = *(const float4*)&Opart[(size_t)32 * Nx * Dx + base];
        const float2 e0 = ML[(size_t)bh * Nx + n0 + n];
        const float2 e1 = ML[(size_t)(32 + bh) * Nx + n0 + n];
        const float M  = fmaxf(e0.x, e1.x);
        const float a0 = exp2f(e0.x - M), a1 = exp2f(e1.x - M);
        const float inv = 1.f / (e0.y * a0 + e1.y * a1);
        const float w0 = a0 * inv, w1 = a1 * inv;
        A[h * 32 + d4 + 0][n] = f0.x * w0 + f1.x * w1;
        A[h * 32 + d4 + 1][n] = f0.y * w0 + f1.y * w1;
        A[h * 32 + d4 + 2][n] = f0.z * w0 + f1.z * w1;
        A[h * 32 + d4 + 3][n] = f0.w * w0 + f1.w * w1;
    }

    float acc[32];
    #pragma unroll
    for (int n = 0; n < 32; ++n) acc[n] = 0.f;

    for (int cc = 0; cc < 16; ++cc) {
        __syncthreads();
        #pragma unroll
        for (int it = 0; it < 4; ++it) {
            const int v = t + it * 256;
            const int o = v >> 2, c4 = (v & 3) * 4;
            const float4 f = *(const float4*)&wp[(size_t)o * 256 + cc * 16 + c4];
            Wl[o][c4 + 0] = f.x; Wl[o][c4 + 1] = f.y;
            Wl[o][c4 + 2] = f.z; Wl[o][c4 + 3] = f.w;
        }
        __syncthreads();
        #pragma unroll
        for (int c = 0; c < 16; ++c) {
            const float wv = Wl[t][c];
            #pragma unroll
            for (int n4 = 0; n4 < 8; ++n4) {
                const float4 a = *(const float4*)&A[cc * 16 + c][n4 * 4];
                acc[n4 * 4 + 0] = fmaf(wv, a.x, acc[n4 * 4 + 0]);
                acc[n4 * 4 + 1] = fmaf(wv, a.y, acc[n4 * 4 + 1]);
                acc[n4 * 4 + 2] = fmaf(wv, a.z, acc[n4 * 4 + 2]);
                acc[n4 * 4 + 3] = fmaf(wv, a.w, acc[n4 * 4 + 3]);
            }
        }
    }

    const float bpv = bp[t];
    #pragma unroll
    for (int n4 = 0; n4 < 8; ++n4) {
        const float4 xr = *(const float4*)&x[((size_t)b * 256 + t) * Nx + n0 + n4 * 4];
        acc[n4 * 4 + 0] += bpv + xr.x;
        acc[n4 * 4 + 1] += bpv + xr.y;
        acc[n4 * 4 + 2] += bpv + xr.z;
        acc[n4 * 4 + 3] += bpv + xr.w;
    }

    __syncthreads();
    #pragma unroll
    for (int n = 0; n < 32; ++n) A[t][n] = acc[n];
    __syncthreads();

    {
        const int nr = t & 31, og = t >> 5;
        float sm = 0.f, sq = 0.f;
        #pragma unroll 8
        for (int oi = 0; oi < 32; ++oi) {
            const float vy = A[og * 32 + oi][nr];
            sm += vy; sq += vy * vy;
        }
        red[og][nr] = sm;
        red[8 + og][nr] = sq;
    }
    __syncthreads();
    if (t < 32) {
        float S = 0.f, Q = 0.f;
        #pragma unroll
        for (int og = 0; og < 8; ++og) { S += red[og][t]; Q += red[8 + og][t]; }
        const float mu  = S * (1.f / 256.f);
        const float var = Q * (1.f / 256.f) - mu * mu;
        mv[0][t] = mu;
        mv[1][t] = rsqrtf(var + 1e-5f);
    }
    __syncthreads();

    const float gv = g[t], bv2 = bb[t];
    float* dst = &out[((size_t)b * 256 + t) * Nx + n0];
    #pragma unroll
    for (int n4 = 0; n4 < 8; ++n4) {
        float4 o4;
        o4.x = (acc[n4 * 4 + 0] - mv[0][n4 * 4 + 0]) * mv[1][n4 * 4 + 0] * gv + bv2;
        o4.y = (acc[n4 * 4 + 1] - mv[0][n4 * 4 + 1]) * mv[1][n4 * 4 + 1] * gv + bv2;
        o4.z = (acc[n4 * 4 + 2] - mv[0][n4 * 4 + 2]) * mv[1][n4 * 4 + 2] * gv + bv2;
        o4.w = (acc[n4 * 4 + 3] - mv[0][n4 * 4 + 3]) * mv[1][n4 * 4 + 3] * gv + bv2;
        *(float4*)(dst + n4 * 4) = o4;
    }
}

// ---------------------------------------------------------------------------
extern "C" void kernel_launch(void* const* d_in, const int* in_sizes, int n_in,
                              void* d_out, int out_size, void* d_ws, size_t ws_size,
                              hipStream_t stream) {
    (void)in_sizes; (void)n_in; (void)out_size; (void)ws_size;
    const float* x      = (const float*)d_in[0];
    const float* w_qkv  = (const float*)d_in[1];
    const float* b_qkv  = (const float*)d_in[2];
    const float* w_proj = (const float*)d_in[3];
    const float* b_proj = (const float*)d_in[4];
    const float* ln_g   = (const float*)d_in[5];
    const float* ln_b   = (const float*)d_in[6];
    float* out = (float*)d_out;

    // workspace layout (29 MB total):
    //   Qb/Kb/Vb bf16 4MB each; Opart fp32 [2][32][2048][32] 16MB; ML 1MB
    unsigned short* Qb = (unsigned short*)d_ws;
    unsigned short* Kb = Qb + (size_t)Bx * Hx * Nx * Dx;
    unsigned short* Vb = Kb + (size_t)Bx * Hx * Nx * Dx;
    float*  Opart = (float*)((char*)d_ws + (size_t)12 * 1024 * 1024);
    float2* ML    = (float2*)((char*)d_ws + (size_t)28 * 1024 * 1024);

    qkv_kernel<<<dim3(12, 16, 4), 256, 0, stream>>>(x, w_qkv, b_qkv, Qb, Kb, Vb);
    attn_kernel<<<dim3(16, 32, 2), 256, 0, stream>>>(Qb, Kb, Vb, Opart, ML);
    proj_ln_kernel<<<dim3(64, 4), 256, 0, stream>>>(Opart, ML, w_proj, b_proj, x,
                                                    ln_g, ln_b, out);
}

// Round 5
// 213.884 us; speedup vs baseline: 1.9696x; 1.0265x over previous
//
#include <hip/hip_runtime.h>
#include <hip/hip_bf16.h>

// Problem constants (fixed by reference): B=4, C=256, N=2048, H=8, D=32
#define Bx 4
#define Cx 256
#define Nx 2048
#define Hx 8
#define Dx 32

typedef __attribute__((ext_vector_type(8))) short bf16x8;   // 8 bf16 (4 VGPRs)
typedef __attribute__((ext_vector_type(4))) float f32x4;

// attention scale folded with log2(e) so softmax can use native exp2:
// (1/sqrt(32)) * 1.4426950408889634
#define QSCALE 0.25503494f

static __device__ __forceinline__ unsigned short f2bf(float f) {
    // round-to-nearest-even bf16
    unsigned int u = __float_as_uint(f);
    u += 0x7fffu + ((u >> 16) & 1u);
    return (unsigned short)(u >> 16);
}

// ---------------------------------------------------------------------------
// Kernel 0: convert inputs to bf16 MFMA layouts.
//   blocks 0..255 : Xt[b][n][c] = bf16(x[b][c][n])   (transpose)
//   blocks 256..259: Wqkvb = bf16(w_qkv) (Q rows pre-scaled), Wpb = bf16(w_proj)
// ---------------------------------------------------------------------------
__global__ __launch_bounds__(256) void convert_kernel(
    const float* __restrict__ x, const float* __restrict__ w_qkv,
    const float* __restrict__ w_proj,
    unsigned short* __restrict__ Xt, unsigned short* __restrict__ Wqkvb,
    unsigned short* __restrict__ Wpb)
{
    const int bx = blockIdx.x, t = threadIdx.x;
    if (bx < 256) {
        const int nb = (bx & 31) * 256 + t;      // 0..8191 over (b,n)
        const int b = nb >> 11, n = nb & 2047;
        const int c0 = (bx >> 5) * 32;
        const float* xb = x + ((size_t)b * Cx) * Nx + n;
        unsigned short* dst = Xt + ((size_t)b * Nx + n) * Cx;
        #pragma unroll
        for (int c8 = 0; c8 < 32; c8 += 8) {
            float f[8];
            #pragma unroll
            for (int j = 0; j < 8; ++j) f[j] = xb[(size_t)(c0 + c8 + j) * Nx];
            uint4 pk;
            pk.x = (unsigned)f2bf(f[0]) | ((unsigned)f2bf(f[1]) << 16);
            pk.y = (unsigned)f2bf(f[2]) | ((unsigned)f2bf(f[3]) << 16);
            pk.z = (unsigned)f2bf(f[4]) | ((unsigned)f2bf(f[5]) << 16);
            pk.w = (unsigned)f2bf(f[6]) | ((unsigned)f2bf(f[7]) << 16);
            *(uint4*)&dst[c0 + c8] = pk;
        }
    } else {
        const int base = (bx - 256) * 65536;
        #pragma unroll 4
        for (int j = 0; j < 64; ++j) {
            const int flat = base + j * 1024 + t * 4;
            if (flat < 768 * 256) {
                const float sc = (flat < 256 * 256) ? QSCALE : 1.0f;
                const float4 f = *(const float4*)&w_qkv[flat];
                ushort4 o;
                o.x = f2bf(f.x * sc); o.y = f2bf(f.y * sc);
                o.z = f2bf(f.z * sc); o.w = f2bf(f.w * sc);
                *(ushort4*)&Wqkvb[flat] = o;
            } else {
                const int f2 = flat - 768 * 256;
                const float4 f = *(const float4*)&w_proj[f2];
                ushort4 o;
                o.x = f2bf(f.x); o.y = f2bf(f.y);
                o.z = f2bf(f.z); o.w = f2bf(f.w);
                *(ushort4*)&Wpb[f2] = o;
            }
        }
    }
}

// ---------------------------------------------------------------------------
// Kernel 1: QKV projection, MFMA, register-direct (no LDS).
// grid (6, 16, 4): o-tile 128, n-tile 128, b.  4 waves (2x2), wave = 64x64.
// region 0/1 (Q/K): D[o][n] = mfma(A=W, B=Xt)  -> Qb/Kb[bh][n][d] ushort4
// region 2   (V) : D[n][o] = mfma(A=Xt, B=W)  -> Vb[bh][d][n]    ushort4
// C/D layout: col = lane&15, row = (lane>>4)*4 + reg.
// ---------------------------------------------------------------------------
__global__ __launch_bounds__(256) void qkv_kernel(
    const unsigned short* __restrict__ Wb, const unsigned short* __restrict__ Xt,
    const float* __restrict__ bias,
    unsigned short* __restrict__ Qb, unsigned short* __restrict__ Kb,
    unsigned short* __restrict__ Vb)
{
    const int t = threadIdx.x;
    const int wv = t >> 6, l = t & 63;
    const int g = l >> 4, c = l & 15;
    const int o0 = blockIdx.x * 128 + (wv >> 1) * 64;
    const int n0 = blockIdx.y * 128 + (wv & 1) * 64;
    const int b  = blockIdx.z;
    const int region = blockIdx.x >> 1;          // 0=Q, 1=K, 2=V

    const unsigned short* XtB = Xt + ((size_t)b * Nx) * Cx;

    f32x4 acc[4][4];
    #pragma unroll
    for (int i = 0; i < 4; ++i)
        #pragma unroll
        for (int j = 0; j < 4; ++j) acc[i][j] = (f32x4){0.f, 0.f, 0.f, 0.f};

    for (int cc = 0; cc < Cx; cc += 32) {
        bf16x8 wf[4], xf[4];
        #pragma unroll
        for (int ti = 0; ti < 4; ++ti)
            wf[ti] = *(const bf16x8*)&Wb[(size_t)(o0 + ti * 16 + c) * Cx + cc + g * 8];
        #pragma unroll
        for (int tj = 0; tj < 4; ++tj)
            xf[tj] = *(const bf16x8*)&XtB[(size_t)(n0 + tj * 16 + c) * Cx + cc + g * 8];
        if (region < 2) {
            #pragma unroll
            for (int ti = 0; ti < 4; ++ti)
                #pragma unroll
                for (int tj = 0; tj < 4; ++tj)
                    acc[ti][tj] = __builtin_amdgcn_mfma_f32_16x16x32_bf16(
                        wf[ti], xf[tj], acc[ti][tj], 0, 0, 0);
        } else {
            #pragma unroll
            for (int ti = 0; ti < 4; ++ti)
                #pragma unroll
                for (int tj = 0; tj < 4; ++tj)
                    acc[ti][tj] = __builtin_amdgcn_mfma_f32_16x16x32_bf16(
                        xf[ti], wf[tj], acc[ti][tj], 0, 0, 0);
        }
    }

    if (region < 2) {
        unsigned short* dst = (region == 0) ? Qb : Kb;
        #pragma unroll
        for (int ti = 0; ti < 4; ++ti) {
            const int o = o0 + ti * 16 + g * 4;               // global channel
            float4 bv = *(const float4*)&bias[o];
            if (region == 0) { bv.x *= QSCALE; bv.y *= QSCALE; bv.z *= QSCALE; bv.w *= QSCALE; }
            const int d0 = o & 31, bh = b * 8 + ((o >> 5) & 7);
            unsigned short* dp = dst + ((size_t)bh * Nx) * Dx + d0;
            #pragma unroll
            for (int tj = 0; tj < 4; ++tj) {
                const int n = n0 + tj * 16 + c;
                ushort4 w4;
                w4.x = f2bf(acc[ti][tj][0] + bv.x);
                w4.y = f2bf(acc[ti][tj][1] + bv.y);
                w4.z = f2bf(acc[ti][tj][2] + bv.z);
                w4.w = f2bf(acc[ti][tj][3] + bv.w);
                *(ushort4*)&dp[(size_t)n * Dx] = w4;
            }
        }
    } else {
        #pragma unroll
        for (int tj = 0; tj < 4; ++tj) {
            const int o = o0 + tj * 16 + c;                   // 512..767
            const float bv = bias[o];
            const int oV = o - 512, d = oV & 31, bh = b * 8 + (oV >> 5);
            unsigned short* dp = Vb + ((size_t)bh * Dx + d) * Nx;
            #pragma unroll
            for (int ti = 0; ti < 4; ++ti) {
                const int n = n0 + ti * 16 + g * 4;
                ushort4 w4;
                w4.x = f2bf(acc[ti][tj][0] + bv);
                w4.y = f2bf(acc[ti][tj][1] + bv);
                w4.z = f2bf(acc[ti][tj][2] + bv);
                w4.w = f2bf(acc[ti][tj][3] + bv);
                *(ushort4*)&dp[n] = w4;
            }
        }
    }
}

// ---------------------------------------------------------------------------
// Kernel 2: MFMA flash attention, 16 q rows per wave, full KV sweep.
// grid (32, 32 bh), block 256 = 4 independent waves (no barriers).
// S^T = K·Q^T (4 MFMA), online softmax in exp2 domain (Q pre-scaled),
// defer-max (threshold 8), P bf16-pair-packed via per-wave LDS (stride 20
// words -> 2-way conflicts = free), O^T = V^T·P^T (4 MFMA).
// Output: final normalized bf16 O in Abf[b][n][h*32+d] (proj B-frag layout).
// ---------------------------------------------------------------------------
__global__ __launch_bounds__(256) void attn_kernel(
    const unsigned short* __restrict__ Qb, const unsigned short* __restrict__ Kb,
    const unsigned short* __restrict__ Vb, unsigned short* __restrict__ Abf)
{
    __shared__ unsigned int Plds[4][32][20];

    const int t  = threadIdx.x;
    const int wv = t >> 6, l = t & 63;
    const int g  = l >> 4, c = l & 15;
    const int q0 = blockIdx.x * 64 + wv * 16;
    const int bh = blockIdx.y;
    const int b = bh >> 3, h = bh & 7;

    const unsigned short* Qp = Qb + (size_t)bh * Nx * Dx;
    const unsigned short* Kp = Kb + (size_t)bh * Nx * Dx;
    const unsigned short* Vp = Vb + (size_t)bh * Dx * Nx;
    unsigned int* pl = &Plds[wv][0][0];

    const bf16x8 qf = *(const bf16x8*)&Qp[(size_t)(q0 + c) * Dx + g * 8];

    f32x4 oacc[2];
    oacc[0] = (f32x4){0.f, 0.f, 0.f, 0.f};
    oacc[1] = (f32x4){0.f, 0.f, 0.f, 0.f};
    float m_i = -3.0e38f, l_i = 0.f;
    const f32x4 zacc = (f32x4){0.f, 0.f, 0.f, 0.f};

    for (int kv0 = 0; kv0 < Nx; kv0 += 64) {
        bf16x8 kf[4];
        #pragma unroll
        for (int ct = 0; ct < 4; ++ct)
            kf[ct] = *(const bf16x8*)&Kp[(size_t)(kv0 + ct * 16 + c) * Dx + g * 8];
        bf16x8 vf[2][2];
        #pragma unroll
        for (int dt = 0; dt < 2; ++dt)
            #pragma unroll
            for (int kc = 0; kc < 2; ++kc)
                vf[dt][kc] = *(const bf16x8*)
                    &Vp[(size_t)(dt * 16 + c) * Nx + kv0 + kc * 32 + g * 8];

        // --- S^T = K·Q^T ---
        f32x4 sacc[4];
        #pragma unroll
        for (int ct = 0; ct < 4; ++ct)
            sacc[ct] = __builtin_amdgcn_mfma_f32_16x16x32_bf16(kf[ct], qf, zacc, 0, 0, 0);

        // --- online softmax (per q-column c) ---
        float mx = -3.0e38f;
        #pragma unroll
        for (int ct = 0; ct < 4; ++ct)
            #pragma unroll
            for (int r = 0; r < 4; ++r) mx = fmaxf(mx, sacc[ct][r]);
        mx = fmaxf(mx, __shfl_xor(mx, 16, 64));
        mx = fmaxf(mx, __shfl_xor(mx, 32, 64));
        if (mx > m_i + 8.f) {          // defer-max: rescale only on real growth
            const float aq = exp2f(m_i - mx);
            m_i = mx;
            l_i *= aq;
            #pragma unroll
            for (int dt = 0; dt < 2; ++dt)
                #pragma unroll
                for (int r = 0; r < 4; ++r) oacc[dt][r] *= aq;
        }
        const float mcur = m_i;
        float rs = 0.f;
        #pragma unroll
        for (int ct = 0; ct < 4; ++ct) {
            float p[4];
            #pragma unroll
            for (int r = 0; r < 4; ++r) {
                p[r] = exp2f(sacc[ct][r] - mcur);
                rs += p[r];
            }
            const unsigned int w0 = (__float_as_uint(p[0]) >> 16) |
                                    (__float_as_uint(p[1]) & 0xffff0000u);
            const unsigned int w1 = (__float_as_uint(p[2]) >> 16) |
                                    (__float_as_uint(p[3]) & 0xffff0000u);
            pl[(ct * 8 + g * 2 + 0) * 20 + c] = w0;
            pl[(ct * 8 + g * 2 + 1) * 20 + c] = w1;
        }
        rs += __shfl_xor(rs, 16, 64);
        rs += __shfl_xor(rs, 32, 64);
        l_i += rs;

        // --- O^T += V^T·P^T ---
        #pragma unroll
        for (int kc = 0; kc < 2; ++kc) {
            union { unsigned int u[4]; bf16x8 v; } bw;
            #pragma unroll
            for (int widx = 0; widx < 4; ++widx)
                bw.u[widx] = pl[(kc * 16 + g * 4 + widx) * 20 + c];
            oacc[0] = __builtin_amdgcn_mfma_f32_16x16x32_bf16(vf[0][kc], bw.v, oacc[0], 0, 0, 0);
            oacc[1] = __builtin_amdgcn_mfma_f32_16x16x32_bf16(vf[1][kc], bw.v, oacc[1], 0, 0, 0);
        }
    }

    // epilogue: normalize, write bf16 O to Abf[b][q][h*32+d]
    const float inv = 1.f / l_i;
    unsigned short* dst = Abf + ((size_t)b * Nx + q0 + c) * Cx + h * 32;
    #pragma unroll
    for (int dt = 0; dt < 2; ++dt) {
        ushort4 w4;
        w4.x = f2bf(oacc[dt][0] * inv);
        w4.y = f2bf(oacc[dt][1] * inv);
        w4.z = f2bf(oacc[dt][2] * inv);
        w4.w = f2bf(oacc[dt][3] * inv);
        *(ushort4*)&dst[dt * 16 + g * 4] = w4;
    }
}

// ---------------------------------------------------------------------------
// Kernel 3: proj MFMA GEMM + bias + residual + LayerNorm, all in registers.
// grid (64, 4): n-tile 32, b.  Block 256 = 4 waves, wave = 64 o x 32 n.
// LN stats: in-register column sums + shfl_xor(16/32) + tiny LDS cross-wave.
// ---------------------------------------------------------------------------
__global__ __launch_bounds__(256) void proj_ln_kernel(
    const unsigned short* __restrict__ Abf, const unsigned short* __restrict__ Wpb,
    const float* __restrict__ bp, const float* __restrict__ x,
    const float* __restrict__ lng, const float* __restrict__ lnb,
    float* __restrict__ out)
{
    __shared__ float red[4][32];
    __shared__ float redq[4][32];
    __shared__ float mv[2][32];

    const int t  = threadIdx.x;
    const int wv = t >> 6, l = t & 63;
    const int lg = l >> 4, lc = l & 15;
    const int n0 = blockIdx.x * 32;
    const int b  = blockIdx.y;
    const int o0 = wv * 64;

    const unsigned short* Ab = Abf + ((size_t)b * Nx) * Cx;

    f32x4 acc[4][2];
    #pragma unroll
    for (int i = 0; i < 4; ++i)
        #pragma unroll
        for (int j = 0; j < 2; ++j) acc[i][j] = (f32x4){0.f, 0.f, 0.f, 0.f};

    for (int cc = 0; cc < Cx; cc += 32) {
        bf16x8 wf[4], af[2];
        #pragma unroll
        for (int ti = 0; ti < 4; ++ti)
            wf[ti] = *(const bf16x8*)&Wpb[(size_t)(o0 + ti * 16 + lc) * Cx + cc + lg * 8];
        #pragma unroll
        for (int tj = 0; tj < 2; ++tj)
            af[tj] = *(const bf16x8*)&Ab[(size_t)(n0 + tj * 16 + lc) * Cx + cc + lg * 8];
        #pragma unroll
        for (int ti = 0; ti < 4; ++ti)
            #pragma unroll
            for (int tj = 0; tj < 2; ++tj)
                acc[ti][tj] = __builtin_amdgcn_mfma_f32_16x16x32_bf16(
                    wf[ti], af[tj], acc[ti][tj], 0, 0, 0);
    }

    // bias + residual, in MFMA layout (o = o0+ti*16+lg*4+r, n = n0+tj*16+lc)
    #pragma unroll
    for (int ti = 0; ti < 4; ++ti) {
        const int o = o0 + ti * 16 + lg * 4;
        const float4 bv = *(const float4*)&bp[o];
        #pragma unroll
        for (int tj = 0; tj < 2; ++tj) {
            const int n = n0 + tj * 16 + lc;
            const float* xp = &x[((size_t)b * Cx + o) * Nx + n];
            acc[ti][tj][0] += bv.x + xp[0];
            acc[ti][tj][1] += bv.y + xp[Nx];
            acc[ti][tj][2] += bv.z + xp[2 * Nx];
            acc[ti][tj][3] += bv.w + xp[3 * Nx];
        }
    }

    // column sums over this wave's 64 o (16 local + shfl over lg groups)
    float s[2] = {0.f, 0.f}, q[2] = {0.f, 0.f};
    #pragma unroll
    for (int ti = 0; ti < 4; ++ti)
        #pragma unroll
        for (int tj = 0; tj < 2; ++tj)
            #pragma unroll
            for (int r = 0; r < 4; ++r) {
                const float v = acc[ti][tj][r];
                s[tj] += v; q[tj] += v * v;
            }
    #pragma unroll
    for (int tj = 0; tj < 2; ++tj) {
        s[tj] += __shfl_xor(s[tj], 16, 64);
        s[tj] += __shfl_xor(s[tj], 32, 64);
        q[tj] += __shfl_xor(q[tj], 16, 64);
        q[tj] += __shfl_xor(q[tj], 32, 64);
    }
    if (lg == 0) {
        #pragma unroll
        for (int tj = 0; tj < 2; ++tj) {
            red[wv][tj * 16 + lc]  = s[tj];
            redq[wv][tj * 16 + lc] = q[tj];
        }
    }
    __syncthreads();
    if (t < 32) {
        const float S = red[0][t] + red[1][t] + red[2][t] + red[3][t];
        const float Q = redq[0][t] + redq[1][t] + redq[2][t] + redq[3][t];
        const float mu  = S * (1.f / 256.f);
        const float var = Q * (1.f / 256.f) - mu * mu;
        mv[0][t] = mu;
        mv[1][t] = rsqrtf(var + 1e-5f);
    }
    __syncthreads();

    float mu_[2], rs_[2];
    #pragma unroll
    for (int tj = 0; tj < 2; ++tj) {
        mu_[tj] = mv[0][tj * 16 + lc];
        rs_[tj] = mv[1][tj * 16 + lc];
    }
    #pragma unroll
    for (int ti = 0; ti < 4; ++ti) {
        const int o = o0 + ti * 16 + lg * 4;
        const float4 g4 = *(const float4*)&lng[o];
        const float4 b4 = *(const float4*)&lnb[o];
        const float gr[4] = {g4.x, g4.y, g4.z, g4.w};
        const float br[4] = {b4.x, b4.y, b4.z, b4.w};
        #pragma unroll
        for (int tj = 0; tj < 2; ++tj) {
            const int n = n0 + tj * 16 + lc;
            float* op = &out[((size_t)b * Cx + o) * Nx + n];
            #pragma unroll
            for (int r = 0; r < 4; ++r)
                op[(size_t)r * Nx] =
                    (acc[ti][tj][r] - mu_[tj]) * rs_[tj] * gr[r] + br[r];
        }
    }
}

// ---------------------------------------------------------------------------
extern "C" void kernel_launch(void* const* d_in, const int* in_sizes, int n_in,
                              void* d_out, int out_size, void* d_ws, size_t ws_size,
                              hipStream_t stream) {
    (void)in_sizes; (void)n_in; (void)out_size; (void)ws_size;
    const float* x      = (const float*)d_in[0];
    const float* w_qkv  = (const float*)d_in[1];
    const float* b_qkv  = (const float*)d_in[2];
    const float* w_proj = (const float*)d_in[3];
    const float* b_proj = (const float*)d_in[4];
    const float* ln_g   = (const float*)d_in[5];
    const float* ln_b   = (const float*)d_in[6];
    float* out = (float*)d_out;

    // workspace (bf16 buffers, ~21 MB total):
    //   Xt  @0       [b][n][c]        4 MB
    //   Wqkvb @4MB   [768][256]       384 KB (Q rows pre-scaled)
    //   Wpb @4.4375MB[256][256]       128 KB
    //   Qb  @5MB     [bh][n][d]       4 MB
    //   Kb  @9MB     [bh][n][d]       4 MB
    //   Vb  @13MB    [bh][d][n]       4 MB
    //   Abf @17MB    [b][n][c]        4 MB
    char* wsb = (char*)d_ws;
    unsigned short* Xt    = (unsigned short*)(wsb);
    unsigned short* Wqkvb = (unsigned short*)(wsb + (size_t)4 * 1024 * 1024);
    unsigned short* Wpb   = (unsigned short*)(wsb + (size_t)4 * 1024 * 1024 + 393216);
    unsigned short* Qb    = (unsigned short*)(wsb + (size_t)5 * 1024 * 1024);
    unsigned short* Kb    = (unsigned short*)(wsb + (size_t)9 * 1024 * 1024);
    unsigned short* Vb    = (unsigned short*)(wsb + (size_t)13 * 1024 * 1024);
    unsigned short* Abf   = (unsigned short*)(wsb + (size_t)17 * 1024 * 1024);

    convert_kernel<<<dim3(260), 256, 0, stream>>>(x, w_qkv, w_proj, Xt, Wqkvb, Wpb);
    qkv_kernel<<<dim3(6, 16, 4), 256, 0, stream>>>(Wqkvb, Xt, b_qkv, Qb, Kb, Vb);
    attn_kernel<<<dim3(32, 32), 256, 0, stream>>>(Qb, Kb, Vb, Abf);
    proj_ln_kernel<<<dim3(64, 4), 256, 0, stream>>>(Abf, Wpb, b_proj, x,
                                                    ln_g, ln_b, out);
}

// Round 6
// 179.957 us; speedup vs baseline: 2.3409x; 1.1885x over previous
//
#include <hip/hip_runtime.h>
#include <hip/hip_bf16.h>

// Problem constants (fixed by reference): B=4, C=256, N=2048, H=8, D=32
#define Bx 4
#define Cx 256
#define Nx 2048
#define Hx 8
#define Dx 32

typedef __attribute__((ext_vector_type(8))) short bf16x8;   // 8 bf16 (4 VGPRs)
typedef __attribute__((ext_vector_type(4))) float f32x4;

// attention scale folded with log2(e) so softmax can use native exp2:
// (1/sqrt(32)) * 1.4426950408889634
#define QSCALE 0.25503494f

static __device__ __forceinline__ unsigned short f2bf(float f) {
    // round-to-nearest-even bf16
    unsigned int u = __float_as_uint(f);
    u += 0x7fffu + ((u >> 16) & 1u);
    return (unsigned short)(u >> 16);
}
static __device__ __forceinline__ float bf2f(unsigned short u) {
    return __uint_as_float(((unsigned int)u) << 16);
}

// ---------------------------------------------------------------------------
// Kernel 0: convert inputs to bf16 MFMA layouts.
//   blocks 0..255 : Xt[b][n][c] = bf16(x[b][c][n])   (transpose)
//   blocks 256..259: Wqkvb = bf16(w_qkv) (Q rows pre-scaled), Wpb = bf16(w_proj)
// ---------------------------------------------------------------------------
__global__ __launch_bounds__(256) void convert_kernel(
    const float* __restrict__ x, const float* __restrict__ w_qkv,
    const float* __restrict__ w_proj,
    unsigned short* __restrict__ Xt, unsigned short* __restrict__ Wqkvb,
    unsigned short* __restrict__ Wpb)
{
    const int bx = blockIdx.x, t = threadIdx.x;
    if (bx < 256) {
        const int nb = (bx & 31) * 256 + t;      // 0..8191 over (b,n)
        const int b = nb >> 11, n = nb & 2047;
        const int c0 = (bx >> 5) * 32;
        const float* xb = x + ((size_t)b * Cx) * Nx + n;
        unsigned short* dst = Xt + ((size_t)b * Nx + n) * Cx;
        #pragma unroll
        for (int c8 = 0; c8 < 32; c8 += 8) {
            float f[8];
            #pragma unroll
            for (int j = 0; j < 8; ++j) f[j] = xb[(size_t)(c0 + c8 + j) * Nx];
            uint4 pk;
            pk.x = (unsigned)f2bf(f[0]) | ((unsigned)f2bf(f[1]) << 16);
            pk.y = (unsigned)f2bf(f[2]) | ((unsigned)f2bf(f[3]) << 16);
            pk.z = (unsigned)f2bf(f[4]) | ((unsigned)f2bf(f[5]) << 16);
            pk.w = (unsigned)f2bf(f[6]) | ((unsigned)f2bf(f[7]) << 16);
            *(uint4*)&dst[c0 + c8] = pk;
        }
    } else {
        const int base = (bx - 256) * 65536;
        #pragma unroll 4
        for (int j = 0; j < 64; ++j) {
            const int flat = base + j * 1024 + t * 4;
            if (flat < 768 * 256) {
                const float sc = (flat < 256 * 256) ? QSCALE : 1.0f;
                const float4 f = *(const float4*)&w_qkv[flat];
                ushort4 o;
                o.x = f2bf(f.x * sc); o.y = f2bf(f.y * sc);
                o.z = f2bf(f.z * sc); o.w = f2bf(f.w * sc);
                *(ushort4*)&Wqkvb[flat] = o;
            } else {
                const int f2 = flat - 768 * 256;
                const float4 f = *(const float4*)&w_proj[f2];
                ushort4 o;
                o.x = f2bf(f.x); o.y = f2bf(f.y);
                o.z = f2bf(f.z); o.w = f2bf(f.w);
                *(ushort4*)&Wpb[f2] = o;
            }
        }
    }
}

// ---------------------------------------------------------------------------
// Kernel 1: QKV projection, MFMA, register-direct (no LDS).
// grid (6, 16, 4): o-tile 128, n-tile 128, b.  4 waves (2x2), wave = 64x64.
// region 0/1 (Q/K): D[o][n] = mfma(A=W, B=Xt)  -> Qb/Kb[bh][n][d] ushort4
// region 2   (V) : D[n][o] = mfma(A=Xt, B=W)  -> Vb[bh][d][n]    ushort4
// C/D layout: col = lane&15, row = (lane>>4)*4 + reg.
// ---------------------------------------------------------------------------
__global__ __launch_bounds__(256) void qkv_kernel(
    const unsigned short* __restrict__ Wb, const unsigned short* __restrict__ Xt,
    const float* __restrict__ bias,
    unsigned short* __restrict__ Qb, unsigned short* __restrict__ Kb,
    unsigned short* __restrict__ Vb)
{
    const int t = threadIdx.x;
    const int wv = t >> 6, l = t & 63;
    const int g = l >> 4, c = l & 15;
    const int o0 = blockIdx.x * 128 + (wv >> 1) * 64;
    const int n0 = blockIdx.y * 128 + (wv & 1) * 64;
    const int b  = blockIdx.z;
    const int region = blockIdx.x >> 1;          // 0=Q, 1=K, 2=V

    const unsigned short* XtB = Xt + ((size_t)b * Nx) * Cx;

    f32x4 acc[4][4];
    #pragma unroll
    for (int i = 0; i < 4; ++i)
        #pragma unroll
        for (int j = 0; j < 4; ++j) acc[i][j] = (f32x4){0.f, 0.f, 0.f, 0.f};

    for (int cc = 0; cc < Cx; cc += 32) {
        bf16x8 wf[4], xf[4];
        #pragma unroll
        for (int ti = 0; ti < 4; ++ti)
            wf[ti] = *(const bf16x8*)&Wb[(size_t)(o0 + ti * 16 + c) * Cx + cc + g * 8];
        #pragma unroll
        for (int tj = 0; tj < 4; ++tj)
            xf[tj] = *(const bf16x8*)&XtB[(size_t)(n0 + tj * 16 + c) * Cx + cc + g * 8];
        if (region < 2) {
            #pragma unroll
            for (int ti = 0; ti < 4; ++ti)
                #pragma unroll
                for (int tj = 0; tj < 4; ++tj)
                    acc[ti][tj] = __builtin_amdgcn_mfma_f32_16x16x32_bf16(
                        wf[ti], xf[tj], acc[ti][tj], 0, 0, 0);
        } else {
            #pragma unroll
            for (int ti = 0; ti < 4; ++ti)
                #pragma unroll
                for (int tj = 0; tj < 4; ++tj)
                    acc[ti][tj] = __builtin_amdgcn_mfma_f32_16x16x32_bf16(
                        xf[ti], wf[tj], acc[ti][tj], 0, 0, 0);
        }
    }

    if (region < 2) {
        unsigned short* dst = (region == 0) ? Qb : Kb;
        #pragma unroll
        for (int ti = 0; ti < 4; ++ti) {
            const int o = o0 + ti * 16 + g * 4;               // global channel
            float4 bv = *(const float4*)&bias[o];
            if (region == 0) { bv.x *= QSCALE; bv.y *= QSCALE; bv.z *= QSCALE; bv.w *= QSCALE; }
            const int d0 = o & 31, bh = b * 8 + ((o >> 5) & 7);
            unsigned short* dp = dst + ((size_t)bh * Nx) * Dx + d0;
            #pragma unroll
            for (int tj = 0; tj < 4; ++tj) {
                const int n = n0 + tj * 16 + c;
                ushort4 w4;
                w4.x = f2bf(acc[ti][tj][0] + bv.x);
                w4.y = f2bf(acc[ti][tj][1] + bv.y);
                w4.z = f2bf(acc[ti][tj][2] + bv.z);
                w4.w = f2bf(acc[ti][tj][3] + bv.w);
                *(ushort4*)&dp[(size_t)n * Dx] = w4;
            }
        }
    } else {
        #pragma unroll
        for (int tj = 0; tj < 4; ++tj) {
            const int o = o0 + tj * 16 + c;                   // 512..767
            const float bv = bias[o];
            const int oV = o - 512, d = oV & 31, bh = b * 8 + (oV >> 5);
            unsigned short* dp = Vb + ((size_t)bh * Dx + d) * Nx;
            #pragma unroll
            for (int ti = 0; ti < 4; ++ti) {
                const int n = n0 + ti * 16 + g * 4;
                ushort4 w4;
                w4.x = f2bf(acc[ti][tj][0] + bv);
                w4.y = f2bf(acc[ti][tj][1] + bv);
                w4.z = f2bf(acc[ti][tj][2] + bv);
                w4.w = f2bf(acc[ti][tj][3] + bv);
                *(ushort4*)&dp[n] = w4;
            }
        }
    }
}

// ---------------------------------------------------------------------------
// Kernel 2: MFMA flash attention, register-resident P (no LDS, no barriers).
// grid (16, 32 bh, 2 z), block 256 = 4 independent waves; wave = 32 q rows,
// KV range [z*1024, z*1024+1024) in 16 tiles of 64.
// Permuted-K trick: kf[t] A-row c loads kv = (c>>2)*8 + (c&3) + {0,4,32,36}[t],
// so S^T output at lane (g,c) reg r is kv = offs_t + g*8 + r, q = c — exactly
// the PV B-fragment k-slot layout after lane-local bf16 pair packing.
// Defer-max (threshold 8, exp2 domain).  Outputs: bf16 partial O^T + (m,l).
// ---------------------------------------------------------------------------
__global__ __launch_bounds__(256, 4) void attn_kernel(
    const unsigned short* __restrict__ Qb, const unsigned short* __restrict__ Kb,
    const unsigned short* __restrict__ Vb, unsigned short* __restrict__ Opart,
    float2* __restrict__ ML)
{
    const int t  = threadIdx.x;
    const int wv = t >> 6, l = t & 63;
    const int g  = l >> 4, c = l & 15;
    const int q0 = blockIdx.x * 128 + wv * 32;
    const int bh = blockIdx.y;
    const int z  = blockIdx.z;

    const unsigned short* Qp = Qb + (size_t)bh * Nx * Dx;
    const unsigned short* Kp = Kb + (size_t)bh * Nx * Dx;
    const unsigned short* Vp = Vb + (size_t)bh * Dx * Nx;

    // Q fragments (B operand): lane holds Q[q0+qt*16+c][g*8 .. +8)
    bf16x8 qf[2];
    #pragma unroll
    for (int qt = 0; qt < 2; ++qt)
        qf[qt] = *(const bf16x8*)&Qp[(size_t)(q0 + qt * 16 + c) * Dx + g * 8];

    f32x4 oacc[2][2];                          // [dt][qt]
    #pragma unroll
    for (int i = 0; i < 2; ++i)
        #pragma unroll
        for (int j = 0; j < 2; ++j)
            oacc[i][j] = (f32x4){0.f, 0.f, 0.f, 0.f};
    float m_i[2] = {-3.0e38f, -3.0e38f};
    float l_i[2] = {0.f, 0.f};
    const f32x4 zacc = (f32x4){0.f, 0.f, 0.f, 0.f};

    const int rowperm = (c >> 2) * 8 + (c & 3);   // permuted K row for tile 0

    const int kv_beg = z * (Nx / 2), kv_end = kv_beg + (Nx / 2);
    for (int kv0 = kv_beg; kv0 < kv_end; kv0 += 64) {
        // K fragments, permuted rows: offs {0,4,32,36}
        bf16x8 kf[4];
        kf[0] = *(const bf16x8*)&Kp[(size_t)(kv0 + rowperm +  0) * Dx + g * 8];
        kf[1] = *(const bf16x8*)&Kp[(size_t)(kv0 + rowperm +  4) * Dx + g * 8];
        kf[2] = *(const bf16x8*)&Kp[(size_t)(kv0 + rowperm + 32) * Dx + g * 8];
        kf[3] = *(const bf16x8*)&Kp[(size_t)(kv0 + rowperm + 36) * Dx + g * 8];
        // V fragments (A of O^T): V^T[dt*16+c][kv0+kc*32+g*8..+8)
        bf16x8 vf[2][2];
        #pragma unroll
        for (int dt = 0; dt < 2; ++dt)
            #pragma unroll
            for (int kc = 0; kc < 2; ++kc)
                vf[dt][kc] = *(const bf16x8*)
                    &Vp[(size_t)(dt * 16 + c) * Nx + kv0 + kc * 32 + g * 8];

        #pragma unroll
        for (int qt = 0; qt < 2; ++qt) {
            // --- S^T = K·Q^T : 4 MFMAs; s[t][r] = S[kv0+offs_t+g*8+r][q] ---
            f32x4 sacc[4];
            #pragma unroll
            for (int ct = 0; ct < 4; ++ct)
                sacc[ct] = __builtin_amdgcn_mfma_f32_16x16x32_bf16(
                    kf[ct], qf[qt], zacc, 0, 0, 0);

            // --- online softmax (per q-column c) ---
            float mx = -3.0e38f;
            #pragma unroll
            for (int ct = 0; ct < 4; ++ct)
                #pragma unroll
                for (int r = 0; r < 4; ++r) mx = fmaxf(mx, sacc[ct][r]);
            mx = fmaxf(mx, __shfl_xor(mx, 16, 64));
            mx = fmaxf(mx, __shfl_xor(mx, 32, 64));
            if (mx > m_i[qt] + 8.f) {      // defer-max, wave-uniform branch
                const float aq = exp2f(m_i[qt] - mx);
                m_i[qt] = mx;
                l_i[qt] *= aq;
                #pragma unroll
                for (int dt = 0; dt < 2; ++dt)
                    #pragma unroll
                    for (int r = 0; r < 4; ++r) oacc[dt][qt][r] *= aq;
            }
            const float mcur = m_i[qt];
            float rs = 0.f;
            unsigned int pw[4][2];         // [tile][word] packed bf16 pairs
            #pragma unroll
            for (int ct = 0; ct < 4; ++ct) {
                float p[4];
                #pragma unroll
                for (int r = 0; r < 4; ++r) {
                    p[r] = exp2f(sacc[ct][r] - mcur);
                    rs += p[r];
                }
                pw[ct][0] = (__float_as_uint(p[0]) >> 16) |
                            (__float_as_uint(p[1]) & 0xffff0000u);
                pw[ct][1] = (__float_as_uint(p[2]) >> 16) |
                            (__float_as_uint(p[3]) & 0xffff0000u);
            }
            rs += __shfl_xor(rs, 16, 64);
            rs += __shfl_xor(rs, 32, 64);
            l_i[qt] += rs;

            // --- O^T += V^T·P^T : P B-fragments are lane-local ---
            #pragma unroll
            for (int kc = 0; kc < 2; ++kc) {
                union { unsigned int u[4]; bf16x8 v; } bw;
                bw.u[0] = pw[kc * 2 + 0][0];
                bw.u[1] = pw[kc * 2 + 0][1];
                bw.u[2] = pw[kc * 2 + 1][0];
                bw.u[3] = pw[kc * 2 + 1][1];
                oacc[0][qt] = __builtin_amdgcn_mfma_f32_16x16x32_bf16(
                    vf[0][kc], bw.v, oacc[0][qt], 0, 0, 0);
                oacc[1][qt] = __builtin_amdgcn_mfma_f32_16x16x32_bf16(
                    vf[1][kc], bw.v, oacc[1][qt], 0, 0, 0);
            }
        }
    }

    // epilogue: store bf16 partial O^T + (m,l), layouts [z][bh][q][d] / [z][bh][q]
    unsigned short* Op = Opart + ((size_t)(z * 32 + bh)) * Nx * Dx;
    float2* Mlp = ML + (size_t)(z * 32 + bh) * Nx;
    #pragma unroll
    for (int qt = 0; qt < 2; ++qt) {
        const int q = q0 + qt * 16 + c;
        if (g == 0) Mlp[q] = make_float2(m_i[qt], l_i[qt]);
        #pragma unroll
        for (int dt = 0; dt < 2; ++dt) {
            ushort4 w4;
            w4.x = f2bf(oacc[dt][qt][0]);
            w4.y = f2bf(oacc[dt][qt][1]);
            w4.z = f2bf(oacc[dt][qt][2]);
            w4.w = f2bf(oacc[dt][qt][3]);
            *(ushort4*)&Op[(size_t)q * Dx + dt * 16 + g * 4] = w4;
        }
    }
}

// ---------------------------------------------------------------------------
// Kernel 2b: merge the two KV-split halves -> normalized bf16 Abf[b][n][h*32+d]
// 524288 threads; thread = one (bh, q, 4-d group).
// ---------------------------------------------------------------------------
__global__ __launch_bounds__(256) void merge_kernel(
    const unsigned short* __restrict__ Opart, const float2* __restrict__ ML,
    unsigned short* __restrict__ Abf)
{
    const int i = blockIdx.x * 256 + threadIdx.x;
    const int qg = i >> 3;                 // (bh,q) 0..65535
    const int d0 = (i & 7) * 4;
    const int bh = qg >> 11, q = qg & 2047;
    const int b = bh >> 3, h = bh & 7;

    const float2 e0 = ML[qg];
    const float2 e1 = ML[65536 + qg];
    const float M  = fmaxf(e0.x, e1.x);
    const float a0 = exp2f(e0.x - M), a1 = exp2f(e1.x - M);
    const float inv = 1.f / (e0.y * a0 + e1.y * a1);
    const float w0 = a0 * inv, w1 = a1 * inv;

    const size_t base = (size_t)qg * Dx + d0;
    const ushort4 p0 = *(const ushort4*)&Opart[base];
    const ushort4 p1 = *(const ushort4*)&Opart[(size_t)65536 * Dx + base];
    ushort4 o;
    o.x = f2bf(bf2f(p0.x) * w0 + bf2f(p1.x) * w1);
    o.y = f2bf(bf2f(p0.y) * w0 + bf2f(p1.y) * w1);
    o.z = f2bf(bf2f(p0.z) * w0 + bf2f(p1.z) * w1);
    o.w = f2bf(bf2f(p0.w) * w0 + bf2f(p1.w) * w1);
    *(ushort4*)&Abf[((size_t)b * Nx + q) * Cx + h * 32 + d0] = o;
}

// ---------------------------------------------------------------------------
// Kernel 3: proj MFMA GEMM + bias + residual + LayerNorm, all in registers.
// grid (64, 4): n-tile 32, b.  Block 256 = 4 waves, wave = 64 o x 32 n.
// LN stats: in-register column sums + shfl_xor(16/32) + tiny LDS cross-wave.
// ---------------------------------------------------------------------------
__global__ __launch_bounds__(256) void proj_ln_kernel(
    const unsigned short* __restrict__ Abf, const unsigned short* __restrict__ Wpb,
    const float* __restrict__ bp, const float* __restrict__ x,
    const float* __restrict__ lng, const float* __restrict__ lnb,
    float* __restrict__ out)
{
    __shared__ float red[4][32];
    __shared__ float redq[4][32];
    __shared__ float mv[2][32];

    const int t  = threadIdx.x;
    const int wv = t >> 6, l = t & 63;
    const int lg = l >> 4, lc = l & 15;
    const int n0 = blockIdx.x * 32;
    const int b  = blockIdx.y;
    const int o0 = wv * 64;

    const unsigned short* Ab = Abf + ((size_t)b * Nx) * Cx;

    f32x4 acc[4][2];
    #pragma unroll
    for (int i = 0; i < 4; ++i)
        #pragma unroll
        for (int j = 0; j < 2; ++j) acc[i][j] = (f32x4){0.f, 0.f, 0.f, 0.f};

    for (int cc = 0; cc < Cx; cc += 32) {
        bf16x8 wf[4], af[2];
        #pragma unroll
        for (int ti = 0; ti < 4; ++ti)
            wf[ti] = *(const bf16x8*)&Wpb[(size_t)(o0 + ti * 16 + lc) * Cx + cc + lg * 8];
        #pragma unroll
        for (int tj = 0; tj < 2; ++tj)
            af[tj] = *(const bf16x8*)&Ab[(size_t)(n0 + tj * 16 + lc) * Cx + cc + lg * 8];
        #pragma unroll
        for (int ti = 0; ti < 4; ++ti)
            #pragma unroll
            for (int tj = 0; tj < 2; ++tj)
                acc[ti][tj] = __builtin_amdgcn_mfma_f32_16x16x32_bf16(
                    wf[ti], af[tj], acc[ti][tj], 0, 0, 0);
    }

    // bias + residual, in MFMA layout (o = o0+ti*16+lg*4+r, n = n0+tj*16+lc)
    #pragma unroll
    for (int ti = 0; ti < 4; ++ti) {
        const int o = o0 + ti * 16 + lg * 4;
        const float4 bv = *(const float4*)&bp[o];
        #pragma unroll
        for (int tj = 0; tj < 2; ++tj) {
            const int n = n0 + tj * 16 + lc;
            const float* xp = &x[((size_t)b * Cx + o) * Nx + n];
            acc[ti][tj][0] += bv.x + xp[0];
            acc[ti][tj][1] += bv.y + xp[Nx];
            acc[ti][tj][2] += bv.z + xp[2 * Nx];
            acc[ti][tj][3] += bv.w + xp[3 * Nx];
        }
    }

    // column sums over this wave's 64 o (16 local + shfl over lg groups)
    float s[2] = {0.f, 0.f}, q[2] = {0.f, 0.f};
    #pragma unroll
    for (int ti = 0; ti < 4; ++ti)
        #pragma unroll
        for (int tj = 0; tj < 2; ++tj)
            #pragma unroll
            for (int r = 0; r < 4; ++r) {
                const float v = acc[ti][tj][r];
                s[tj] += v; q[tj] += v * v;
            }
    #pragma unroll
    for (int tj = 0; tj < 2; ++tj) {
        s[tj] += __shfl_xor(s[tj], 16, 64);
        s[tj] += __shfl_xor(s[tj], 32, 64);
        q[tj] += __shfl_xor(q[tj], 16, 64);
        q[tj] += __shfl_xor(q[tj], 32, 64);
    }
    if (lg == 0) {
        #pragma unroll
        for (int tj = 0; tj < 2; ++tj) {
            red[wv][tj * 16 + lc]  = s[tj];
            redq[wv][tj * 16 + lc] = q[tj];
        }
    }
    __syncthreads();
    if (t < 32) {
        const float S = red[0][t] + red[1][t] + red[2][t] + red[3][t];
        const float Q = redq[0][t] + redq[1][t] + redq[2][t] + redq[3][t];
        const float mu  = S * (1.f / 256.f);
        const float var = Q * (1.f / 256.f) - mu * mu;
        mv[0][t] = mu;
        mv[1][t] = rsqrtf(var + 1e-5f);
    }
    __syncthreads();

    float mu_[2], rs_[2];
    #pragma unroll
    for (int tj = 0; tj < 2; ++tj) {
        mu_[tj] = mv[0][tj * 16 + lc];
        rs_[tj] = mv[1][tj * 16 + lc];
    }
    #pragma unroll
    for (int ti = 0; ti < 4; ++ti) {
        const int o = o0 + ti * 16 + lg * 4;
        const float4 g4 = *(const float4*)&lng[o];
        const float4 b4 = *(const float4*)&lnb[o];
        const float gr[4] = {g4.x, g4.y, g4.z, g4.w};
        const float br[4] = {b4.x, b4.y, b4.z, b4.w};
        #pragma unroll
        for (int tj = 0; tj < 2; ++tj) {
            const int n = n0 + tj * 16 + lc;
            float* op = &out[((size_t)b * Cx + o) * Nx + n];
            #pragma unroll
            for (int r = 0; r < 4; ++r)
                op[(size_t)r * Nx] =
                    (acc[ti][tj][r] - mu_[tj]) * rs_[tj] * gr[r] + br[r];
        }
    }
}

// ---------------------------------------------------------------------------
extern "C" void kernel_launch(void* const* d_in, const int* in_sizes, int n_in,
                              void* d_out, int out_size, void* d_ws, size_t ws_size,
                              hipStream_t stream) {
    (void)in_sizes; (void)n_in; (void)out_size; (void)ws_size;
    const float* x      = (const float*)d_in[0];
    const float* w_qkv  = (const float*)d_in[1];
    const float* b_qkv  = (const float*)d_in[2];
    const float* w_proj = (const float*)d_in[3];
    const float* b_proj = (const float*)d_in[4];
    const float* ln_g   = (const float*)d_in[5];
    const float* ln_b   = (const float*)d_in[6];
    float* out = (float*)d_out;

    // workspace (~30 MB):
    //   Xt  @0       [b][n][c] bf16       4 MB
    //   Wqkvb @4MB   [768][256] bf16      384 KB (Q rows pre-scaled)
    //   Wpb @4.4MB   [256][256] bf16      128 KB
    //   Qb  @5MB     [bh][n][d] bf16      4 MB
    //   Kb  @9MB     [bh][n][d] bf16      4 MB
    //   Vb  @13MB    [bh][d][n] bf16      4 MB
    //   Abf @17MB    [b][n][c]  bf16      4 MB
    //   Opart @21MB  [2][bh][n][d] bf16   8 MB
    //   ML  @29MB    [2][bh][n] float2    1 MB
    char* wsb = (char*)d_ws;
    unsigned short* Xt    = (unsigned short*)(wsb);
    unsigned short* Wqkvb = (unsigned short*)(wsb + (size_t)4 * 1024 * 1024);
    unsigned short* Wpb   = (unsigned short*)(wsb + (size_t)4 * 1024 * 1024 + 393216);
    unsigned short* Qb    = (unsigned short*)(wsb + (size_t)5 * 1024 * 1024);
    unsigned short* Kb    = (unsigned short*)(wsb + (size_t)9 * 1024 * 1024);
    unsigned short* Vb    = (unsigned short*)(wsb + (size_t)13 * 1024 * 1024);
    unsigned short* Abf   = (unsigned short*)(wsb + (size_t)17 * 1024 * 1024);
    unsigned short* Opart = (unsigned short*)(wsb + (size_t)21 * 1024 * 1024);
    float2*         ML    = (float2*)(wsb + (size_t)29 * 1024 * 1024);

    convert_kernel<<<dim3(260), 256, 0, stream>>>(x, w_qkv, w_proj, Xt, Wqkvb, Wpb);
    qkv_kernel<<<dim3(6, 16, 4), 256, 0, stream>>>(Wqkvb, Xt, b_qkv, Qb, Kb, Vb);
    attn_kernel<<<dim3(16, 32, 2), 256, 0, stream>>>(Qb, Kb, Vb, Opart, ML);
    merge_kernel<<<dim3(2048), 256, 0, stream>>>(Opart, ML, Abf);
    proj_ln_kernel<<<dim3(64, 4), 256, 0, stream>>>(Abf, Wpb, b_proj, x,
                                                    ln_g, ln_b, out);
}

// Round 7
// 159.066 us; speedup vs baseline: 2.6483x; 1.1313x over previous
//
#include <hip/hip_runtime.h>
#include <hip/hip_bf16.h>

// Problem constants (fixed by reference): B=4, C=256, N=2048, H=8, D=32
#define Bx 4
#define Cx 256
#define Nx 2048
#define Hx 8
#define Dx 32

typedef __attribute__((ext_vector_type(8))) short bf16x8;   // 8 bf16 (4 VGPRs)
typedef __attribute__((ext_vector_type(4))) float f32x4;

// attention scale folded with log2(e) so softmax can use native exp2:
// (1/sqrt(32)) * 1.4426950408889634
#define QSCALE 0.25503494f

static __device__ __forceinline__ unsigned short f2bf(float f) {
    // round-to-nearest-even bf16
    unsigned int u = __float_as_uint(f);
    u += 0x7fffu + ((u >> 16) & 1u);
    return (unsigned short)(u >> 16);
}
static __device__ __forceinline__ float bf2f(unsigned short u) {
    return __uint_as_float(((unsigned int)u) << 16);
}

// ---------------------------------------------------------------------------
// Kernel 0: convert inputs to bf16 MFMA layouts.
//   blocks 0..511  : Xt[b][n][c] = bf16(x[b][c][n])  (transpose; 16 c/thread)
//   blocks 512..639: Wqkvb = bf16(w_qkv) (Q rows pre-scaled), Wpb = bf16(w_proj)
// ---------------------------------------------------------------------------
__global__ __launch_bounds__(256) void convert_kernel(
    const float* __restrict__ x, const float* __restrict__ w_qkv,
    const float* __restrict__ w_proj,
    unsigned short* __restrict__ Xt, unsigned short* __restrict__ Wqkvb,
    unsigned short* __restrict__ Wpb)
{
    const int bx = blockIdx.x, t = threadIdx.x;
    if (bx < 512) {
        const int nb = (bx & 31) * 256 + t;      // 0..8191 over (b,n)
        const int b = nb >> 11, n = nb & 2047;
        const int c0 = (bx >> 5) * 16;           // 16 c-groups
        const float* xb = x + (size_t)b * Cx * Nx + n;
        unsigned short* dst = Xt + ((size_t)b * Nx + n) * Cx;
        #pragma unroll
        for (int c8 = 0; c8 < 16; c8 += 8) {
            float f[8];
            #pragma unroll
            for (int j = 0; j < 8; ++j) f[j] = xb[(size_t)(c0 + c8 + j) * Nx];
            uint4 pk;
            pk.x = (unsigned)f2bf(f[0]) | ((unsigned)f2bf(f[1]) << 16);
            pk.y = (unsigned)f2bf(f[2]) | ((unsigned)f2bf(f[3]) << 16);
            pk.z = (unsigned)f2bf(f[4]) | ((unsigned)f2bf(f[5]) << 16);
            pk.w = (unsigned)f2bf(f[6]) | ((unsigned)f2bf(f[7]) << 16);
            *(uint4*)&dst[c0 + c8] = pk;
        }
    } else {
        const int flat = (bx - 512) * 2048 + t * 8;
        #pragma unroll
        for (int hh = 0; hh < 8; hh += 4) {
            const int f0 = flat + hh;
            if (f0 < 768 * 256) {
                const float sc = (f0 < 65536) ? QSCALE : 1.0f;
                const float4 f = *(const float4*)&w_qkv[f0];
                ushort4 o;
                o.x = f2bf(f.x * sc); o.y = f2bf(f.y * sc);
                o.z = f2bf(f.z * sc); o.w = f2bf(f.w * sc);
                *(ushort4*)&Wqkvb[f0] = o;
            } else {
                const int f2v = f0 - 768 * 256;
                const float4 f = *(const float4*)&w_proj[f2v];
                ushort4 o;
                o.x = f2bf(f.x); o.y = f2bf(f.y);
                o.z = f2bf(f.z); o.w = f2bf(f.w);
                *(ushort4*)&Wpb[f2v] = o;
            }
        }
    }
}

// ---------------------------------------------------------------------------
// Kernel 1: QKV projection, MFMA, register-direct (no LDS).
// grid (12, 16, 4), 4 waves; wave tile = 32o x 64n (3 waves/SIMD).
// XCD-bijective swizzle: all o-tiles of one (n-tile,b) land on one XCD.
// region 0/1 (Q/K): D[o][n] = mfma(A=W, B=Xt)  -> Qb/Kb[bh][n][d] ushort4
// region 2   (V) : D[n][o] = mfma(A=Xt, B=W)  -> Vb[bh][d][n]    ushort4
// C/D layout: col = lane&15, row = (lane>>4)*4 + reg.
// ---------------------------------------------------------------------------
__global__ __launch_bounds__(256) void qkv_kernel(
    const unsigned short* __restrict__ Wb, const unsigned short* __restrict__ Xt,
    const float* __restrict__ bias,
    unsigned short* __restrict__ Qb, unsigned short* __restrict__ Kb,
    unsigned short* __restrict__ Vb)
{
    const int t = threadIdx.x;
    const int wv = t >> 6, l = t & 63;
    const int g = l >> 4, c = l & 15;

    // swizzle: lin -> (xcd, s); x-tile varies within an XCD, (y,z) pinned to it
    const int lin = blockIdx.x + 12 * (blockIdx.y + 16 * blockIdx.z);
    const int xcd = lin & 7, s = lin >> 3;          // s in 0..95
    const int xb = s % 12;
    const int yz = (s / 12) * 8 + xcd;              // 0..63
    const int yb = yz & 15, b = yz >> 4;

    const int o0 = xb * 64 + (wv >> 1) * 32;
    const int n0 = yb * 128 + (wv & 1) * 64;
    const int region = xb >> 2;                     // 0=Q, 1=K, 2=V

    const unsigned short* XtB = Xt + (size_t)b * Nx * Cx;

    if (region < 2) {
        f32x4 acc[2][4];
        #pragma unroll
        for (int i = 0; i < 2; ++i)
            #pragma unroll
            for (int j = 0; j < 4; ++j) acc[i][j] = (f32x4){0.f, 0.f, 0.f, 0.f};

        for (int cc = 0; cc < Cx; cc += 32) {
            bf16x8 wf[2], xf[4];
            #pragma unroll
            for (int ti = 0; ti < 2; ++ti)
                wf[ti] = *(const bf16x8*)&Wb[(size_t)(o0 + ti * 16 + c) * Cx + cc + g * 8];
            #pragma unroll
            for (int tj = 0; tj < 4; ++tj)
                xf[tj] = *(const bf16x8*)&XtB[(size_t)(n0 + tj * 16 + c) * Cx + cc + g * 8];
            #pragma unroll
            for (int ti = 0; ti < 2; ++ti)
                #pragma unroll
                for (int tj = 0; tj < 4; ++tj)
                    acc[ti][tj] = __builtin_amdgcn_mfma_f32_16x16x32_bf16(
                        wf[ti], xf[tj], acc[ti][tj], 0, 0, 0);
        }

        unsigned short* dst = (region == 0) ? Qb : Kb;
        #pragma unroll
        for (int ti = 0; ti < 2; ++ti) {
            const int o = o0 + ti * 16 + g * 4;
            float4 bv = *(const float4*)&bias[o];
            if (region == 0) { bv.x *= QSCALE; bv.y *= QSCALE; bv.z *= QSCALE; bv.w *= QSCALE; }
            const int d0 = o & 31, bh = b * 8 + ((o >> 5) & 7);
            unsigned short* dp = dst + (size_t)bh * Nx * Dx + d0;
            #pragma unroll
            for (int tj = 0; tj < 4; ++tj) {
                const int n = n0 + tj * 16 + c;
                ushort4 w4;
                w4.x = f2bf(acc[ti][tj][0] + bv.x);
                w4.y = f2bf(acc[ti][tj][1] + bv.y);
                w4.z = f2bf(acc[ti][tj][2] + bv.z);
                w4.w = f2bf(acc[ti][tj][3] + bv.w);
                *(ushort4*)&dp[(size_t)n * Dx] = w4;
            }
        }
    } else {
        f32x4 acc[4][2];
        #pragma unroll
        for (int i = 0; i < 4; ++i)
            #pragma unroll
            for (int j = 0; j < 2; ++j) acc[i][j] = (f32x4){0.f, 0.f, 0.f, 0.f};

        for (int cc = 0; cc < Cx; cc += 32) {
            bf16x8 wf[2], xf[4];
            #pragma unroll
            for (int ot = 0; ot < 2; ++ot)
                wf[ot] = *(const bf16x8*)&Wb[(size_t)(o0 + ot * 16 + c) * Cx + cc + g * 8];
            #pragma unroll
            for (int nt = 0; nt < 4; ++nt)
                xf[nt] = *(const bf16x8*)&XtB[(size_t)(n0 + nt * 16 + c) * Cx + cc + g * 8];
            #pragma unroll
            for (int nt = 0; nt < 4; ++nt)
                #pragma unroll
                for (int ot = 0; ot < 2; ++ot)
                    acc[nt][ot] = __builtin_amdgcn_mfma_f32_16x16x32_bf16(
                        xf[nt], wf[ot], acc[nt][ot], 0, 0, 0);
        }

        #pragma unroll
        for (int ot = 0; ot < 2; ++ot) {
            const int o = o0 + ot * 16 + c;                   // 512..767
            const float bv = bias[o];
            const int oV = o - 512, d = oV & 31, bh = b * 8 + (oV >> 5);
            unsigned short* dp = Vb + ((size_t)bh * Dx + d) * Nx;
            #pragma unroll
            for (int nt = 0; nt < 4; ++nt) {
                const int n = n0 + nt * 16 + g * 4;
                ushort4 w4;
                w4.x = f2bf(acc[nt][ot][0] + bv);
                w4.y = f2bf(acc[nt][ot][1] + bv);
                w4.z = f2bf(acc[nt][ot][2] + bv);
                w4.w = f2bf(acc[nt][ot][3] + bv);
                *(ushort4*)&dp[n] = w4;
            }
        }
    }
}

// ---------------------------------------------------------------------------
// Kernel 2: MFMA flash attention, register-resident P (no LDS, no barriers).
// grid (16, 32, 2) with XCD-bijective swizzle: all 32 blocks of one bh land
// on xcd = bh%8 (K/V L2-resident per XCD).  Wave = 32 q rows, half KV range.
// Permuted-K trick: kf[t] A-row c loads kv = (c>>2)*8 + (c&3) + {0,4,32,36}[t],
// so S^T output at lane (g,c) reg r is kv = offs_t + g*8 + r, q = c — exactly
// the PV B-fragment k-slot layout after lane-local bf16 pair packing.
// Defer-max (threshold 8, exp2 domain).  Outputs: bf16 partial O^T + (m,l).
// ---------------------------------------------------------------------------
__global__ __launch_bounds__(256, 4) void attn_kernel(
    const unsigned short* __restrict__ Qb, const unsigned short* __restrict__ Kb,
    const unsigned short* __restrict__ Vb, unsigned short* __restrict__ Opart,
    float2* __restrict__ ML)
{
    const int t  = threadIdx.x;
    const int wv = t >> 6, l = t & 63;
    const int g  = l >> 4, c = l & 15;

    // swizzle: bh pinned to xcd = bh & 7
    const int lin = blockIdx.x + 16 * blockIdx.y + 512 * blockIdx.z;
    const int xcd = lin & 7, s = lin >> 3;          // s in 0..127
    const int bh = ((s & 3) << 3) | xcd;
    const int qt_ = (s >> 2) & 15;
    const int z  = s >> 6;
    const int q0 = qt_ * 128 + wv * 32;

    const unsigned short* Qp = Qb + (size_t)bh * Nx * Dx;
    const unsigned short* Kp = Kb + (size_t)bh * Nx * Dx;
    const unsigned short* Vp = Vb + (size_t)bh * Dx * Nx;

    // Q fragments (B operand): lane holds Q[q0+qt*16+c][g*8 .. +8)
    bf16x8 qf[2];
    #pragma unroll
    for (int qt = 0; qt < 2; ++qt)
        qf[qt] = *(const bf16x8*)&Qp[(size_t)(q0 + qt * 16 + c) * Dx + g * 8];

    f32x4 oacc[2][2];                          // [dt][qt]
    #pragma unroll
    for (int i = 0; i < 2; ++i)
        #pragma unroll
        for (int j = 0; j < 2; ++j)
            oacc[i][j] = (f32x4){0.f, 0.f, 0.f, 0.f};
    float m_i[2] = {-3.0e38f, -3.0e38f};
    float l_i[2] = {0.f, 0.f};
    const f32x4 zacc = (f32x4){0.f, 0.f, 0.f, 0.f};

    const int rowperm = (c >> 2) * 8 + (c & 3);   // permuted K row for tile 0

    const int kv_beg = z * (Nx / 2), kv_end = kv_beg + (Nx / 2);
    for (int kv0 = kv_beg; kv0 < kv_end; kv0 += 64) {
        // K fragments, permuted rows: offs {0,4,32,36}
        bf16x8 kf[4];
        kf[0] = *(const bf16x8*)&Kp[(size_t)(kv0 + rowperm +  0) * Dx + g * 8];
        kf[1] = *(const bf16x8*)&Kp[(size_t)(kv0 + rowperm +  4) * Dx + g * 8];
        kf[2] = *(const bf16x8*)&Kp[(size_t)(kv0 + rowperm + 32) * Dx + g * 8];
        kf[3] = *(const bf16x8*)&Kp[(size_t)(kv0 + rowperm + 36) * Dx + g * 8];
        // V fragments (A of O^T): V^T[dt*16+c][kv0+kc*32+g*8..+8)
        bf16x8 vf[2][2];
        #pragma unroll
        for (int dt = 0; dt < 2; ++dt)
            #pragma unroll
            for (int kc = 0; kc < 2; ++kc)
                vf[dt][kc] = *(const bf16x8*)
                    &Vp[(size_t)(dt * 16 + c) * Nx + kv0 + kc * 32 + g * 8];

        #pragma unroll
        for (int qt = 0; qt < 2; ++qt) {
            // --- S^T = K·Q^T : 4 MFMAs; s[t][r] = S[kv0+offs_t+g*8+r][q] ---
            f32x4 sacc[4];
            #pragma unroll
            for (int ct = 0; ct < 4; ++ct)
                sacc[ct] = __builtin_amdgcn_mfma_f32_16x16x32_bf16(
                    kf[ct], qf[qt], zacc, 0, 0, 0);

            // --- online softmax (per q-column c) ---
            float mx = -3.0e38f;
            #pragma unroll
            for (int ct = 0; ct < 4; ++ct)
                #pragma unroll
                for (int r = 0; r < 4; ++r) mx = fmaxf(mx, sacc[ct][r]);
            mx = fmaxf(mx, __shfl_xor(mx, 16, 64));
            mx = fmaxf(mx, __shfl_xor(mx, 32, 64));
            if (mx > m_i[qt] + 8.f) {      // defer-max, wave-uniform branch
                const float aq = exp2f(m_i[qt] - mx);
                m_i[qt] = mx;
                l_i[qt] *= aq;
                #pragma unroll
                for (int dt = 0; dt < 2; ++dt)
                    #pragma unroll
                    for (int r = 0; r < 4; ++r) oacc[dt][qt][r] *= aq;
            }
            const float mcur = m_i[qt];
            float rs = 0.f;
            unsigned int pw[4][2];         // [tile][word] packed bf16 pairs
            #pragma unroll
            for (int ct = 0; ct < 4; ++ct) {
                float p[4];
                #pragma unroll
                for (int r = 0; r < 4; ++r) {
                    p[r] = exp2f(sacc[ct][r] - mcur);
                    rs += p[r];
                }
                pw[ct][0] = (__float_as_uint(p[0]) >> 16) |
                            (__float_as_uint(p[1]) & 0xffff0000u);
                pw[ct][1] = (__float_as_uint(p[2]) >> 16) |
                            (__float_as_uint(p[3]) & 0xffff0000u);
            }
            rs += __shfl_xor(rs, 16, 64);
            rs += __shfl_xor(rs, 32, 64);
            l_i[qt] += rs;

            // --- O^T += V^T·P^T : P B-fragments are lane-local ---
            #pragma unroll
            for (int kc = 0; kc < 2; ++kc) {
                union { unsigned int u[4]; bf16x8 v; } bw;
                bw.u[0] = pw[kc * 2 + 0][0];
                bw.u[1] = pw[kc * 2 + 0][1];
                bw.u[2] = pw[kc * 2 + 1][0];
                bw.u[3] = pw[kc * 2 + 1][1];
                oacc[0][qt] = __builtin_amdgcn_mfma_f32_16x16x32_bf16(
                    vf[0][kc], bw.v, oacc[0][qt], 0, 0, 0);
                oacc[1][qt] = __builtin_amdgcn_mfma_f32_16x16x32_bf16(
                    vf[1][kc], bw.v, oacc[1][qt], 0, 0, 0);
            }
        }
    }

    // epilogue: store bf16 partial O^T + (m,l), layouts [z][bh][q][d] / [z][bh][q]
    unsigned short* Op = Opart + ((size_t)(z * 32 + bh)) * Nx * Dx;
    float2* Mlp = ML + (size_t)(z * 32 + bh) * Nx;
    #pragma unroll
    for (int qt = 0; qt < 2; ++qt) {
        const int q = q0 + qt * 16 + c;
        if (g == 0) Mlp[q] = make_float2(m_i[qt], l_i[qt]);
        #pragma unroll
        for (int dt = 0; dt < 2; ++dt) {
            ushort4 w4;
            w4.x = f2bf(oacc[dt][qt][0]);
            w4.y = f2bf(oacc[dt][qt][1]);
            w4.z = f2bf(oacc[dt][qt][2]);
            w4.w = f2bf(oacc[dt][qt][3]);
            *(ushort4*)&Op[(size_t)q * Dx + dt * 16 + g * 4] = w4;
        }
    }
}

// ---------------------------------------------------------------------------
// Kernel 3: fused {KV-split merge + proj MFMA GEMM + bias + residual + LN}.
// grid (128, 4): n-tile 16, b.  Block 256 = 4 waves, wave = 64 o x 16 n
// (2 waves/SIMD).  The merged A-fragment is built on the fly from Opart + ML.
// LN stats: in-register column sums + shfl_xor(16/32) + tiny LDS cross-wave.
// ---------------------------------------------------------------------------
__global__ __launch_bounds__(256) void proj_ln_kernel(
    const unsigned short* __restrict__ Opart, const float2* __restrict__ ML,
    const unsigned short* __restrict__ Wpb,
    const float* __restrict__ bp, const float* __restrict__ x,
    const float* __restrict__ lng, const float* __restrict__ lnb,
    float* __restrict__ out)
{
    __shared__ float red[4][16];
    __shared__ float redq[4][16];
    __shared__ float mv[2][16];

    const int t  = threadIdx.x;
    const int wv = t >> 6, l = t & 63;
    const int lg = l >> 4, lc = l & 15;
    const int n0 = blockIdx.x * 16;
    const int b  = blockIdx.y;
    const int o0 = wv * 64;
    const int n  = n0 + lc;

    f32x4 acc[4];
    #pragma unroll
    for (int i = 0; i < 4; ++i) acc[i] = (f32x4){0.f, 0.f, 0.f, 0.f};

    for (int cc = 0; cc < Cx; cc += 32) {
        const int h = cc >> 5;
        const int bh = b * 8 + h;
        // merge weights for (bh, n)
        const float2 e0 = ML[(size_t)bh * Nx + n];
        const float2 e1 = ML[(size_t)(32 + bh) * Nx + n];
        const float M  = fmaxf(e0.x, e1.x);
        const float a0 = exp2f(e0.x - M), a1 = exp2f(e1.x - M);
        const float inv = 1.f / (e0.y * a0 + e1.y * a1);
        const float w0 = a0 * inv, w1 = a1 * inv;
        // merged A fragment: 8 bf16 at d = lg*8 .. +8
        const size_t obase = ((size_t)bh * Nx + n) * Dx + lg * 8;
        const uint4 u0 = *(const uint4*)&Opart[obase];
        const uint4 u1 = *(const uint4*)&Opart[(size_t)65536 * Dx + obase];
        const unsigned int u0w[4] = {u0.x, u0.y, u0.z, u0.w};
        const unsigned int u1w[4] = {u1.x, u1.y, u1.z, u1.w};
        union { unsigned int u[4]; bf16x8 v; } af;
        #pragma unroll
        for (int wi = 0; wi < 4; ++wi) {
            const float lo = bf2f((unsigned short)(u0w[wi] & 0xffffu)) * w0 +
                             bf2f((unsigned short)(u1w[wi] & 0xffffu)) * w1;
            const float hi = bf2f((unsigned short)(u0w[wi] >> 16)) * w0 +
                             bf2f((unsigned short)(u1w[wi] >> 16)) * w1;
            af.u[wi] = (unsigned int)f2bf(lo) | ((unsigned int)f2bf(hi) << 16);
        }
        // W fragments + MFMA
        #pragma unroll
        for (int ti = 0; ti < 4; ++ti) {
            const bf16x8 wf = *(const bf16x8*)
                &Wpb[(size_t)(o0 + ti * 16 + lc) * Cx + cc + lg * 8];
            acc[ti] = __builtin_amdgcn_mfma_f32_16x16x32_bf16(wf, af.v, acc[ti], 0, 0, 0);
        }
    }

    // bias + residual (o = o0+ti*16+lg*4+r, col n)
    #pragma unroll
    for (int ti = 0; ti < 4; ++ti) {
        const int o = o0 + ti * 16 + lg * 4;
        const float4 bv = *(const float4*)&bp[o];
        const float* xp = &x[((size_t)b * Cx + o) * Nx + n];
        acc[ti][0] += bv.x + xp[0];
        acc[ti][1] += bv.y + xp[Nx];
        acc[ti][2] += bv.z + xp[2 * Nx];
        acc[ti][3] += bv.w + xp[3 * Nx];
    }

    // column sums over this wave's 64 o
    float s_ = 0.f, q_ = 0.f;
    #pragma unroll
    for (int ti = 0; ti < 4; ++ti)
        #pragma unroll
        for (int r = 0; r < 4; ++r) {
            const float v = acc[ti][r];
            s_ += v; q_ += v * v;
        }
    s_ += __shfl_xor(s_, 16, 64);
    s_ += __shfl_xor(s_, 32, 64);
    q_ += __shfl_xor(q_, 16, 64);
    q_ += __shfl_xor(q_, 32, 64);
    if (lg == 0) { red[wv][lc] = s_; redq[wv][lc] = q_; }
    __syncthreads();
    if (t < 16) {
        const float S = red[0][t] + red[1][t] + red[2][t] + red[3][t];
        const float Q = redq[0][t] + redq[1][t] + redq[2][t] + redq[3][t];
        const float mu  = S * (1.f / 256.f);
        const float var = Q * (1.f / 256.f) - mu * mu;
        mv[0][t] = mu;
        mv[1][t] = rsqrtf(var + 1e-5f);
    }
    __syncthreads();

    const float mu_ = mv[0][lc], rs_ = mv[1][lc];
    #pragma unroll
    for (int ti = 0; ti < 4; ++ti) {
        const int o = o0 + ti * 16 + lg * 4;
        const float4 g4 = *(const float4*)&lng[o];
        const float4 b4 = *(const float4*)&lnb[o];
        const float gr[4] = {g4.x, g4.y, g4.z, g4.w};
        const float br[4] = {b4.x, b4.y, b4.z, b4.w};
        float* op = &out[((size_t)b * Cx + o) * Nx + n];
        #pragma unroll
        for (int r = 0; r < 4; ++r)
            op[(size_t)r * Nx] = (acc[ti][r] - mu_) * rs_ * gr[r] + br[r];
    }
}

// ---------------------------------------------------------------------------
extern "C" void kernel_launch(void* const* d_in, const int* in_sizes, int n_in,
                              void* d_out, int out_size, void* d_ws, size_t ws_size,
                              hipStream_t stream) {
    (void)in_sizes; (void)n_in; (void)out_size; (void)ws_size;
    const float* x      = (const float*)d_in[0];
    const float* w_qkv  = (const float*)d_in[1];
    const float* b_qkv  = (const float*)d_in[2];
    const float* w_proj = (const float*)d_in[3];
    const float* b_proj = (const float*)d_in[4];
    const float* ln_g   = (const float*)d_in[5];
    const float* ln_b   = (const float*)d_in[6];
    float* out = (float*)d_out;

    // workspace (~30 MB):
    //   Xt  @0       [b][n][c] bf16       4 MB
    //   Wqkvb @4MB   [768][256] bf16      384 KB (Q rows pre-scaled)
    //   Wpb @4.4MB   [256][256] bf16      128 KB
    //   Qb  @5MB     [bh][n][d] bf16      4 MB
    //   Kb  @9MB     [bh][n][d] bf16      4 MB
    //   Vb  @13MB    [bh][d][n] bf16      4 MB
    //   Opart @21MB  [2][bh][n][d] bf16   8 MB
    //   ML  @29MB    [2][bh][n] float2    1 MB
    char* wsb = (char*)d_ws;
    unsigned short* Xt    = (unsigned short*)(wsb);
    unsigned short* Wqkvb = (unsigned short*)(wsb + (size_t)4 * 1024 * 1024);
    unsigned short* Wpb   = (unsigned short*)(wsb + (size_t)4 * 1024 * 1024 + 393216);
    unsigned short* Qb    = (unsigned short*)(wsb + (size_t)5 * 1024 * 1024);
    unsigned short* Kb    = (unsigned short*)(wsb + (size_t)9 * 1024 * 1024);
    unsigned short* Vb    = (unsigned short*)(wsb + (size_t)13 * 1024 * 1024);
    unsigned short* Opart = (unsigned short*)(wsb + (size_t)21 * 1024 * 1024);
    float2*         ML    = (float2*)(wsb + (size_t)29 * 1024 * 1024);

    convert_kernel<<<dim3(640), 256, 0, stream>>>(x, w_qkv, w_proj, Xt, Wqkvb, Wpb);
    qkv_kernel<<<dim3(12, 16, 4), 256, 0, stream>>>(Wqkvb, Xt, b_qkv, Qb, Kb, Vb);
    attn_kernel<<<dim3(16, 32, 2), 256, 0, stream>>>(Qb, Kb, Vb, Opart, ML);
    proj_ln_kernel<<<dim3(128, 4), 256, 0, stream>>>(Opart, ML, Wpb, b_proj, x,
                                                     ln_g, ln_b, out);
}

// Round 8
// 155.871 us; speedup vs baseline: 2.7026x; 1.0205x over previous
//
#include <hip/hip_runtime.h>
#include <hip/hip_bf16.h>

// Problem constants (fixed by reference): B=4, C=256, N=2048, H=8, D=32
#define Bx 4
#define Cx 256
#define Nx 2048
#define Hx 8
#define Dx 32

typedef __attribute__((ext_vector_type(8))) short bf16x8;   // 8 bf16 (4 VGPRs)
typedef __attribute__((ext_vector_type(4))) float f32x4;

// attention scale folded with log2(e) so softmax can use native exp2:
// (1/sqrt(32)) * 1.4426950408889634
#define QSCALE 0.25503494f

static __device__ __forceinline__ unsigned short f2bf(float f) {
    // round-to-nearest-even bf16
    unsigned int u = __float_as_uint(f);
    u += 0x7fffu + ((u >> 16) & 1u);
    return (unsigned short)(u >> 16);
}
static __device__ __forceinline__ float bf2f(unsigned short u) {
    return __uint_as_float(((unsigned int)u) << 16);
}
// raw hardware exp2 / rcp (no libm range fixup; CDNA hw interlocks cover
// trans-op latency)
static __device__ __forceinline__ float fexp2(float x) {
    float r;
    asm("v_exp_f32 %0, %1" : "=v"(r) : "v"(x));
    return r;
}
static __device__ __forceinline__ float frcp(float x) {
    float r;
    asm("v_rcp_f32 %0, %1" : "=v"(r) : "v"(x));
    return r;
}

// ---------------------------------------------------------------------------
// Kernel 0: convert inputs to bf16 MFMA layouts.
//   blocks 0..511  : Xt[b][n][c] = bf16(x[b][c][n])  (transpose; 16 c/thread)
//   blocks 512..639: Wqkvb = bf16(w_qkv) (Q rows pre-scaled), Wpb = bf16(w_proj)
// ---------------------------------------------------------------------------
__global__ __launch_bounds__(256) void convert_kernel(
    const float* __restrict__ x, const float* __restrict__ w_qkv,
    const float* __restrict__ w_proj,
    unsigned short* __restrict__ Xt, unsigned short* __restrict__ Wqkvb,
    unsigned short* __restrict__ Wpb)
{
    const int bx = blockIdx.x, t = threadIdx.x;
    if (bx < 512) {
        const int nb = (bx & 31) * 256 + t;      // 0..8191 over (b,n)
        const int b = nb >> 11, n = nb & 2047;
        const int c0 = (bx >> 5) * 16;           // 16 c-groups
        const float* xb = x + (size_t)b * Cx * Nx + n;
        unsigned short* dst = Xt + ((size_t)b * Nx + n) * Cx;
        #pragma unroll
        for (int c8 = 0; c8 < 16; c8 += 8) {
            float f[8];
            #pragma unroll
            for (int j = 0; j < 8; ++j) f[j] = xb[(size_t)(c0 + c8 + j) * Nx];
            uint4 pk;
            pk.x = (unsigned)f2bf(f[0]) | ((unsigned)f2bf(f[1]) << 16);
            pk.y = (unsigned)f2bf(f[2]) | ((unsigned)f2bf(f[3]) << 16);
            pk.z = (unsigned)f2bf(f[4]) | ((unsigned)f2bf(f[5]) << 16);
            pk.w = (unsigned)f2bf(f[6]) | ((unsigned)f2bf(f[7]) << 16);
            *(uint4*)&dst[c0 + c8] = pk;
        }
    } else {
        const int flat = (bx - 512) * 2048 + t * 8;
        #pragma unroll
        for (int hh = 0; hh < 8; hh += 4) {
            const int f0 = flat + hh;
            if (f0 < 768 * 256) {
                const float sc = (f0 < 65536) ? QSCALE : 1.0f;
                const float4 f = *(const float4*)&w_qkv[f0];
                ushort4 o;
                o.x = f2bf(f.x * sc); o.y = f2bf(f.y * sc);
                o.z = f2bf(f.z * sc); o.w = f2bf(f.w * sc);
                *(ushort4*)&Wqkvb[f0] = o;
            } else {
                const int f2v = f0 - 768 * 256;
                const float4 f = *(const float4*)&w_proj[f2v];
                ushort4 o;
                o.x = f2bf(f.x); o.y = f2bf(f.y);
                o.z = f2bf(f.z); o.w = f2bf(f.w);
                *(ushort4*)&Wpb[f2v] = o;
            }
        }
    }
}

// ---------------------------------------------------------------------------
// Kernel 1: QKV projection, MFMA, register-direct (no LDS).
// grid (12, 16, 4), 4 waves; wave tile = 32o x 64n (3 waves/SIMD).
// XCD-bijective swizzle: all o-tiles of one (n-tile,b) land on one XCD.
// region 0/1 (Q/K): D[o][n] = mfma(A=W, B=Xt)  -> Qb/Kb[bh][n][d] ushort4
// region 2   (V) : D[n][o] = mfma(A=Xt, B=W)  -> Vb[bh][d][n]    ushort4
// C/D layout: col = lane&15, row = (lane>>4)*4 + reg.
// ---------------------------------------------------------------------------
__global__ __launch_bounds__(256) void qkv_kernel(
    const unsigned short* __restrict__ Wb, const unsigned short* __restrict__ Xt,
    const float* __restrict__ bias,
    unsigned short* __restrict__ Qb, unsigned short* __restrict__ Kb,
    unsigned short* __restrict__ Vb)
{
    const int t = threadIdx.x;
    const int wv = t >> 6, l = t & 63;
    const int g = l >> 4, c = l & 15;

    // swizzle: lin -> (xcd, s); x-tile varies within an XCD, (y,z) pinned to it
    const int lin = blockIdx.x + 12 * (blockIdx.y + 16 * blockIdx.z);
    const int xcd = lin & 7, s = lin >> 3;          // s in 0..95
    const int xb = s % 12;
    const int yz = (s / 12) * 8 + xcd;              // 0..63
    const int yb = yz & 15, b = yz >> 4;

    const int o0 = xb * 64 + (wv >> 1) * 32;
    const int n0 = yb * 128 + (wv & 1) * 64;
    const int region = xb >> 2;                     // 0=Q, 1=K, 2=V

    const unsigned short* XtB = Xt + (size_t)b * Nx * Cx;

    if (region < 2) {
        f32x4 acc[2][4];
        #pragma unroll
        for (int i = 0; i < 2; ++i)
            #pragma unroll
            for (int j = 0; j < 4; ++j) acc[i][j] = (f32x4){0.f, 0.f, 0.f, 0.f};

        for (int cc = 0; cc < Cx; cc += 32) {
            bf16x8 wf[2], xf[4];
            #pragma unroll
            for (int ti = 0; ti < 2; ++ti)
                wf[ti] = *(const bf16x8*)&Wb[(size_t)(o0 + ti * 16 + c) * Cx + cc + g * 8];
            #pragma unroll
            for (int tj = 0; tj < 4; ++tj)
                xf[tj] = *(const bf16x8*)&XtB[(size_t)(n0 + tj * 16 + c) * Cx + cc + g * 8];
            #pragma unroll
            for (int ti = 0; ti < 2; ++ti)
                #pragma unroll
                for (int tj = 0; tj < 4; ++tj)
                    acc[ti][tj] = __builtin_amdgcn_mfma_f32_16x16x32_bf16(
                        wf[ti], xf[tj], acc[ti][tj], 0, 0, 0);
        }

        unsigned short* dst = (region == 0) ? Qb : Kb;
        #pragma unroll
        for (int ti = 0; ti < 2; ++ti) {
            const int o = o0 + ti * 16 + g * 4;
            float4 bv = *(const float4*)&bias[o];
            if (region == 0) { bv.x *= QSCALE; bv.y *= QSCALE; bv.z *= QSCALE; bv.w *= QSCALE; }
            const int d0 = o & 31, bh = b * 8 + ((o >> 5) & 7);
            unsigned short* dp = dst + (size_t)bh * Nx * Dx + d0;
            #pragma unroll
            for (int tj = 0; tj < 4; ++tj) {
                const int n = n0 + tj * 16 + c;
                ushort4 w4;
                w4.x = f2bf(acc[ti][tj][0] + bv.x);
                w4.y = f2bf(acc[ti][tj][1] + bv.y);
                w4.z = f2bf(acc[ti][tj][2] + bv.z);
                w4.w = f2bf(acc[ti][tj][3] + bv.w);
                *(ushort4*)&dp[(size_t)n * Dx] = w4;
            }
        }
    } else {
        f32x4 acc[4][2];
        #pragma unroll
        for (int i = 0; i < 4; ++i)
            #pragma unroll
            for (int j = 0; j < 2; ++j) acc[i][j] = (f32x4){0.f, 0.f, 0.f, 0.f};

        for (int cc = 0; cc < Cx; cc += 32) {
            bf16x8 wf[2], xf[4];
            #pragma unroll
            for (int ot = 0; ot < 2; ++ot)
                wf[ot] = *(const bf16x8*)&Wb[(size_t)(o0 + ot * 16 + c) * Cx + cc + g * 8];
            #pragma unroll
            for (int nt = 0; nt < 4; ++nt)
                xf[nt] = *(const bf16x8*)&XtB[(size_t)(n0 + nt * 16 + c) * Cx + cc + g * 8];
            #pragma unroll
            for (int nt = 0; nt < 4; ++nt)
                #pragma unroll
                for (int ot = 0; ot < 2; ++ot)
                    acc[nt][ot] = __builtin_amdgcn_mfma_f32_16x16x32_bf16(
                        xf[nt], wf[ot], acc[nt][ot], 0, 0, 0);
        }

        #pragma unroll
        for (int ot = 0; ot < 2; ++ot) {
            const int o = o0 + ot * 16 + c;                   // 512..767
            const float bv = bias[o];
            const int oV = o - 512, d = oV & 31, bh = b * 8 + (oV >> 5);
            unsigned short* dp = Vb + ((size_t)bh * Dx + d) * Nx;
            #pragma unroll
            for (int nt = 0; nt < 4; ++nt) {
                const int n = n0 + nt * 16 + g * 4;
                ushort4 w4;
                w4.x = f2bf(acc[nt][ot][0] + bv);
                w4.y = f2bf(acc[nt][ot][1] + bv);
                w4.z = f2bf(acc[nt][ot][2] + bv);
                w4.w = f2bf(acc[nt][ot][3] + bv);
                *(ushort4*)&dp[n] = w4;
            }
        }
    }
}

// ---------------------------------------------------------------------------
// Kernel 2: MFMA flash attention, register-resident P (no LDS, no barriers).
// grid (16, 32, 2) with XCD-bijective swizzle (bh pinned to xcd = bh%8).
// Wave = 32 q rows, half KV range in 16 tiles of 64.
// Permuted-K trick: kf[t] A-row c loads kv = (c>>2)*8 + (c&3) + {0,4,32,36}[t],
// so S^T output at lane (g,c) reg r is kv = offs_t + g*8 + r, q = c — exactly
// the PV B-fragment k-slot layout after lane-local bf16 pair packing.
// VALU-path optimizations (this round):
//   - raw v_exp_f32 (no libm fixup)
//   - lane-local defer-max precheck + __any gate (uniform branch; common path
//     has NO cross-lane shfl at all)
//   - softmax denominator l via MFMA ones-trick (rides idle matrix pipe)
// Outputs: bf16 partial O^T + (m,l).
// ---------------------------------------------------------------------------
__global__ __launch_bounds__(256, 4) void attn_kernel(
    const unsigned short* __restrict__ Qb, const unsigned short* __restrict__ Kb,
    const unsigned short* __restrict__ Vb, unsigned short* __restrict__ Opart,
    float2* __restrict__ ML)
{
    const int t  = threadIdx.x;
    const int wv = t >> 6, l = t & 63;
    const int g  = l >> 4, c = l & 15;

    // swizzle: bh pinned to xcd = bh & 7
    const int lin = blockIdx.x + 16 * blockIdx.y + 512 * blockIdx.z;
    const int xcd = lin & 7, s = lin >> 3;          // s in 0..127
    const int bh = ((s & 3) << 3) | xcd;
    const int qt_ = (s >> 2) & 15;
    const int z  = s >> 6;
    const int q0 = qt_ * 128 + wv * 32;

    const unsigned short* Qp = Qb + (size_t)bh * Nx * Dx;
    const unsigned short* Kp = Kb + (size_t)bh * Nx * Dx;
    const unsigned short* Vp = Vb + (size_t)bh * Dx * Nx;

    // Q fragments (B operand): lane holds Q[q0+qt*16+c][g*8 .. +8)
    bf16x8 qf[2];
    #pragma unroll
    for (int qt = 0; qt < 2; ++qt)
        qf[qt] = *(const bf16x8*)&Qp[(size_t)(q0 + qt * 16 + c) * Dx + g * 8];

    // ones fragment (bf16 1.0 x8) for the l-sum MFMA
    union { unsigned int u[4]; bf16x8 v; } onesf;
    onesf.u[0] = onesf.u[1] = onesf.u[2] = onesf.u[3] = 0x3F803F80u;

    f32x4 oacc[2][2];                          // [dt][qt]
    f32x4 lacc[2];                             // [qt] — all 4 regs identical
    #pragma unroll
    for (int i = 0; i < 2; ++i) {
        lacc[i] = (f32x4){0.f, 0.f, 0.f, 0.f};
        #pragma unroll
        for (int j = 0; j < 2; ++j)
            oacc[i][j] = (f32x4){0.f, 0.f, 0.f, 0.f};
    }
    float m_i[2] = {-3.0e38f, -3.0e38f};
    const f32x4 zacc = (f32x4){0.f, 0.f, 0.f, 0.f};

    const int rowperm = (c >> 2) * 8 + (c & 3);   // permuted K row for tile 0

    const int kv_beg = z * (Nx / 2), kv_end = kv_beg + (Nx / 2);
    for (int kv0 = kv_beg; kv0 < kv_end; kv0 += 64) {
        // K fragments, permuted rows: offs {0,4,32,36}
        bf16x8 kf[4];
        kf[0] = *(const bf16x8*)&Kp[(size_t)(kv0 + rowperm +  0) * Dx + g * 8];
        kf[1] = *(const bf16x8*)&Kp[(size_t)(kv0 + rowperm +  4) * Dx + g * 8];
        kf[2] = *(const bf16x8*)&Kp[(size_t)(kv0 + rowperm + 32) * Dx + g * 8];
        kf[3] = *(const bf16x8*)&Kp[(size_t)(kv0 + rowperm + 36) * Dx + g * 8];
        // V fragments (A of O^T): V^T[dt*16+c][kv0+kc*32+g*8..+8)
        bf16x8 vf[2][2];
        #pragma unroll
        for (int dt = 0; dt < 2; ++dt)
            #pragma unroll
            for (int kc = 0; kc < 2; ++kc)
                vf[dt][kc] = *(const bf16x8*)
                    &Vp[(size_t)(dt * 16 + c) * Nx + kv0 + kc * 32 + g * 8];

        #pragma unroll
        for (int qt = 0; qt < 2; ++qt) {
            // --- S^T = K·Q^T : 4 MFMAs; s[t][r] = S[kv0+offs_t+g*8+r][q] ---
            f32x4 sacc[4];
            #pragma unroll
            for (int ct = 0; ct < 4; ++ct)
                sacc[ct] = __builtin_amdgcn_mfma_f32_16x16x32_bf16(
                    kf[ct], qf[qt], zacc, 0, 0, 0);

            // --- lane-local max (v_max3-friendly tree) ---
            float tm[4];
            #pragma unroll
            for (int ct = 0; ct < 4; ++ct)
                tm[ct] = fmaxf(fmaxf(fmaxf(sacc[ct][0], sacc[ct][1]),
                                     sacc[ct][2]), sacc[ct][3]);
            const float mxl = fmaxf(fmaxf(fmaxf(tm[0], tm[1]), tm[2]), tm[3]);

            // defer-max: uniform-gated; common path skips shfl AND rescale.
            // (column max = max of 4 lanes' local maxes, all sharing m_i[qt])
            if (__any(mxl > m_i[qt] + 8.f)) {
                float mx = fmaxf(mxl, __shfl_xor(mxl, 16, 64));
                mx = fmaxf(mx, __shfl_xor(mx, 32, 64));
                const float mnew = fmaxf(m_i[qt], mx);
                const float aq = fexp2(m_i[qt] - mnew);
                m_i[qt] = mnew;
                #pragma unroll
                for (int dt = 0; dt < 2; ++dt)
                    #pragma unroll
                    for (int r = 0; r < 4; ++r) oacc[dt][qt][r] *= aq;
                #pragma unroll
                for (int r = 0; r < 4; ++r) lacc[qt][r] *= aq;
            }
            const float mcur = m_i[qt];
            unsigned int pw[4][2];         // [tile][word] packed bf16 pairs
            #pragma unroll
            for (int ct = 0; ct < 4; ++ct) {
                float p[4];
                #pragma unroll
                for (int r = 0; r < 4; ++r) p[r] = fexp2(sacc[ct][r] - mcur);
                pw[ct][0] = (__float_as_uint(p[0]) >> 16) |
                            (__float_as_uint(p[1]) & 0xffff0000u);
                pw[ct][1] = (__float_as_uint(p[2]) >> 16) |
                            (__float_as_uint(p[3]) & 0xffff0000u);
            }

            // --- O^T += V^T·P^T ; l += 1^T·P^T (matrix pipe) ---
            #pragma unroll
            for (int kc = 0; kc < 2; ++kc) {
                union { unsigned int u[4]; bf16x8 v; } bw;
                bw.u[0] = pw[kc * 2 + 0][0];
                bw.u[1] = pw[kc * 2 + 0][1];
                bw.u[2] = pw[kc * 2 + 1][0];
                bw.u[3] = pw[kc * 2 + 1][1];
                oacc[0][qt] = __builtin_amdgcn_mfma_f32_16x16x32_bf16(
                    vf[0][kc], bw.v, oacc[0][qt], 0, 0, 0);
                oacc[1][qt] = __builtin_amdgcn_mfma_f32_16x16x32_bf16(
                    vf[1][kc], bw.v, oacc[1][qt], 0, 0, 0);
                lacc[qt] = __builtin_amdgcn_mfma_f32_16x16x32_bf16(
                    onesf.v, bw.v, lacc[qt], 0, 0, 0);
            }
        }
    }

    // epilogue: store bf16 partial O^T + (m,l), layouts [z][bh][q][d] / [z][bh][q]
    unsigned short* Op = Opart + ((size_t)(z * 32 + bh)) * Nx * Dx;
    float2* Mlp = ML + (size_t)(z * 32 + bh) * Nx;
    #pragma unroll
    for (int qt = 0; qt < 2; ++qt) {
        const int q = q0 + qt * 16 + c;
        if (g == 0) Mlp[q] = make_float2(m_i[qt], lacc[qt][0]);
        #pragma unroll
        for (int dt = 0; dt < 2; ++dt) {
            ushort4 w4;
            w4.x = f2bf(oacc[dt][qt][0]);
            w4.y = f2bf(oacc[dt][qt][1]);
            w4.z = f2bf(oacc[dt][qt][2]);
            w4.w = f2bf(oacc[dt][qt][3]);
            *(ushort4*)&Op[(size_t)q * Dx + dt * 16 + g * 4] = w4;
        }
    }
}

// ---------------------------------------------------------------------------
// Kernel 3: fused {KV-split merge + proj MFMA GEMM + bias + residual + LN}.
// grid (128, 4): n-tile 16, b.  Block 256 = 4 waves, wave = 64 o x 16 n
// (2 waves/SIMD).  The merged A-fragment is built on the fly from Opart + ML.
// LN stats: in-register column sums + shfl_xor(16/32) + tiny LDS cross-wave.
// ---------------------------------------------------------------------------
__global__ __launch_bounds__(256) void proj_ln_kernel(
    const unsigned short* __restrict__ Opart, const float2* __restrict__ ML,
    const unsigned short* __restrict__ Wpb,
    const float* __restrict__ bp, const float* __restrict__ x,
    const float* __restrict__ lng, const float* __restrict__ lnb,
    float* __restrict__ out)
{
    __shared__ float red[4][16];
    __shared__ float redq[4][16];
    __shared__ float mv[2][16];

    const int t  = threadIdx.x;
    const int wv = t >> 6, l = t & 63;
    const int lg = l >> 4, lc = l & 15;
    const int n0 = blockIdx.x * 16;
    const int b  = blockIdx.y;
    const int o0 = wv * 64;
    const int n  = n0 + lc;

    f32x4 acc[4];
    #pragma unroll
    for (int i = 0; i < 4; ++i) acc[i] = (f32x4){0.f, 0.f, 0.f, 0.f};

    for (int cc = 0; cc < Cx; cc += 32) {
        const int h = cc >> 5;
        const int bh = b * 8 + h;
        // merge weights for (bh, n)
        const float2 e0 = ML[(size_t)bh * Nx + n];
        const float2 e1 = ML[(size_t)(32 + bh) * Nx + n];
        const float M  = fmaxf(e0.x, e1.x);
        const float a0 = fexp2(e0.x - M), a1 = fexp2(e1.x - M);
        const float inv = frcp(e0.y * a0 + e1.y * a1);
        const float w0 = a0 * inv, w1 = a1 * inv;
        // merged A fragment: 8 bf16 at d = lg*8 .. +8
        const size_t obase = ((size_t)bh * Nx + n) * Dx + lg * 8;
        const uint4 u0 = *(const uint4*)&Opart[obase];
        const uint4 u1 = *(const uint4*)&Opart[(size_t)65536 * Dx + obase];
        const unsigned int u0w[4] = {u0.x, u0.y, u0.z, u0.w};
        const unsigned int u1w[4] = {u1.x, u1.y, u1.z, u1.w};
        union { unsigned int u[4]; bf16x8 v; } af;
        #pragma unroll
        for (int wi = 0; wi < 4; ++wi) {
            const float lo = bf2f((unsigned short)(u0w[wi] & 0xffffu)) * w0 +
                             bf2f((unsigned short)(u1w[wi] & 0xffffu)) * w1;
            const float hi = bf2f((unsigned short)(u0w[wi] >> 16)) * w0 +
                             bf2f((unsigned short)(u1w[wi] >> 16)) * w1;
            af.u[wi] = (unsigned int)f2bf(lo) | ((unsigned int)f2bf(hi) << 16);
        }
        // W fragments + MFMA
        #pragma unroll
        for (int ti = 0; ti < 4; ++ti) {
            const bf16x8 wf = *(const bf16x8*)
                &Wpb[(size_t)(o0 + ti * 16 + lc) * Cx + cc + lg * 8];
            acc[ti] = __builtin_amdgcn_mfma_f32_16x16x32_bf16(wf, af.v, acc[ti], 0, 0, 0);
        }
    }

    // bias + residual (o = o0+ti*16+lg*4+r, col n)
    #pragma unroll
    for (int ti = 0; ti < 4; ++ti) {
        const int o = o0 + ti * 16 + lg * 4;
        const float4 bv = *(const float4*)&bp[o];
        const float* xp = &x[((size_t)b * Cx + o) * Nx + n];
        acc[ti][0] += bv.x + xp[0];
        acc[ti][1] += bv.y + xp[Nx];
        acc[ti][2] += bv.z + xp[2 * Nx];
        acc[ti][3] += bv.w + xp[3 * Nx];
    }

    // column sums over this wave's 64 o
    float s_ = 0.f, q_ = 0.f;
    #pragma unroll
    for (int ti = 0; ti < 4; ++ti)
        #pragma unroll
        for (int r = 0; r < 4; ++r) {
            const float v = acc[ti][r];
            s_ += v; q_ += v * v;
        }
    s_ += __shfl_xor(s_, 16, 64);
    s_ += __shfl_xor(s_, 32, 64);
    q_ += __shfl_xor(q_, 16, 64);
    q_ += __shfl_xor(q_, 32, 64);
    if (lg == 0) { red[wv][lc] = s_; redq[wv][lc] = q_; }
    __syncthreads();
    if (t < 16) {
        const float S = red[0][t] + red[1][t] + red[2][t] + red[3][t];
        const float Q = redq[0][t] + redq[1][t] + redq[2][t] + redq[3][t];
        const float mu  = S * (1.f / 256.f);
        const float var = Q * (1.f / 256.f) - mu * mu;
        mv[0][t] = mu;
        mv[1][t] = rsqrtf(var + 1e-5f);
    }
    __syncthreads();

    const float mu_ = mv[0][lc], rs_ = mv[1][lc];
    #pragma unroll
    for (int ti = 0; ti < 4; ++ti) {
        const int o = o0 + ti * 16 + lg * 4;
        const float4 g4 = *(const float4*)&lng[o];
        const float4 b4 = *(const float4*)&lnb[o];
        const float gr[4] = {g4.x, g4.y, g4.z, g4.w};
        const float br[4] = {b4.x, b4.y, b4.z, b4.w};
        float* op = &out[((size_t)b * Cx + o) * Nx + n];
        #pragma unroll
        for (int r = 0; r < 4; ++r)
            op[(size_t)r * Nx] = (acc[ti][r] - mu_) * rs_ * gr[r] + br[r];
    }
}

// ---------------------------------------------------------------------------
extern "C" void kernel_launch(void* const* d_in, const int* in_sizes, int n_in,
                              void* d_out, int out_size, void* d_ws, size_t ws_size,
                              hipStream_t stream) {
    (void)in_sizes; (void)n_in; (void)out_size; (void)ws_size;
    const float* x      = (const float*)d_in[0];
    const float* w_qkv  = (const float*)d_in[1];
    const float* b_qkv  = (const float*)d_in[2];
    const float* w_proj = (const float*)d_in[3];
    const float* b_proj = (const float*)d_in[4];
    const float* ln_g   = (const float*)d_in[5];
    const float* ln_b   = (const float*)d_in[6];
    float* out = (float*)d_out;

    // workspace (~30 MB):
    //   Xt  @0       [b][n][c] bf16       4 MB
    //   Wqkvb @4MB   [768][256] bf16      384 KB (Q rows pre-scaled)
    //   Wpb @4.4MB   [256][256] bf16      128 KB
    //   Qb  @5MB     [bh][n][d] bf16      4 MB
    //   Kb  @9MB     [bh][n][d] bf16      4 MB
    //   Vb  @13MB    [bh][d][n] bf16      4 MB
    //   Opart @21MB  [2][bh][n][d] bf16   8 MB
    //   ML  @29MB    [2][bh][n] float2    1 MB
    char* wsb = (char*)d_ws;
    unsigned short* Xt    = (unsigned short*)(wsb);
    unsigned short* Wqkvb = (unsigned short*)(wsb + (size_t)4 * 1024 * 1024);
    unsigned short* Wpb   = (unsigned short*)(wsb + (size_t)4 * 1024 * 1024 + 393216);
    unsigned short* Qb    = (unsigned short*)(wsb + (size_t)5 * 1024 * 1024);
    unsigned short* Kb    = (unsigned short*)(wsb + (size_t)9 * 1024 * 1024);
    unsigned short* Vb    = (unsigned short*)(wsb + (size_t)13 * 1024 * 1024);
    unsigned short* Opart = (unsigned short*)(wsb + (size_t)21 * 1024 * 1024);
    float2*         ML    = (float2*)(wsb + (size_t)29 * 1024 * 1024);

    convert_kernel<<<dim3(640), 256, 0, stream>>>(x, w_qkv, w_proj, Xt, Wqkvb, Wpb);
    qkv_kernel<<<dim3(12, 16, 4), 256, 0, stream>>>(Wqkvb, Xt, b_qkv, Qb, Kb, Vb);
    attn_kernel<<<dim3(16, 32, 2), 256, 0, stream>>>(Qb, Kb, Vb, Opart, ML);
    proj_ln_kernel<<<dim3(128, 4), 256, 0, stream>>>(Opart, ML, Wpb, b_proj, x,
                                                     ln_g, ln_b, out);
}